// Round 9
// baseline (207.913 us; speedup 1.0000x reference)
//
#include <hip/hip_runtime.h>
#include <hip/hip_bf16.h>
#include <cstdint>
#include <cstddef>

#define DEVI __device__ __forceinline__

static constexpr int SEQ = 2048;
static constexpr int DM  = 1024;
static constexpr int NH  = 16;
static constexpr int HD  = 64;
static constexpr int NTOK = 2 * SEQ;
static constexpr int NBUCKET = 257;
static constexpr float LOG2E = 1.44269504088896f;

typedef __attribute__((ext_vector_type(8))) short bf16x8;
typedef __attribute__((ext_vector_type(4))) float f32x4;
typedef __attribute__((ext_vector_type(16))) float f32x16;
typedef __attribute__((ext_vector_type(2))) unsigned int uint32x2;
#define MFMA16(a, b, c) __builtin_amdgcn_mfma_f32_16x16x32_bf16((a), (b), (c), 0, 0, 0)
#define MFMA32(a, b, c) __builtin_amdgcn_mfma_f32_32x32x16_bf16((a), (b), (c), 0, 0, 0)

DEVI float bf1(uint16_t u)  { return __uint_as_float(((uint32_t)u) << 16); }
DEVI uint16_t f2bf(float f) {
    uint32_t x = __float_as_uint(f);
    x += 0x7fffu + ((x >> 16) & 1u);   // RTNE
    return (uint16_t)(x >> 16);
}
DEVI bf16x8 ld_frag(const uint16_t* p) {
    union { uint4 u; bf16x8 f; } c;
    c.u = *(const uint4*)p;
    return c.f;
}
DEVI void gld16(const uint16_t* g, uint16_t* l) {
    __builtin_amdgcn_global_load_lds(
        (const __attribute__((address_space(1))) uint32_t*)g,
        (__attribute__((address_space(3))) uint32_t*)l, 16, 0, 0);
}
// Guide-verified T12 primitives (proven green in v13).
DEVI uint32_t cvt_pk_bf16(float lo, float hi) {
    uint32_t r;
    asm("v_cvt_pk_bf16_f32 %0, %1, %2" : "=v"(r) : "v"(lo), "v"(hi));
    return r;
}
DEVI void pl32(uint32_t &a, uint32_t &b) {
    const uint32x2 r = __builtin_amdgcn_permlane32_swap(a, b, false, false);
    a = r[0]; b = r[1];
}

// ============================================================
__global__ void sniff_kernel(const uint16_t* __restrict__ x, int* __restrict__ flag)
{
    int bad = 0;
    for (int i = threadIdx.x; i < 512; i += 64) {
        const float v = bf1(x[i]);
        if (!(fabsf(v) < 64.0f)) bad = 1;
    }
    const unsigned long long m = __ballot(bad);
    if (threadIdx.x == 0) *flag = (m != 0ull) ? 1 : 0;
}

// ============================================================
__global__ __launch_bounds__(256)
void convert_kernel(const void* __restrict__ x, const void* __restrict__ Wq,
                    const void* __restrict__ Wk, const void* __restrict__ Wv,
                    const void* __restrict__ Wo, const void* __restrict__ bq,
                    const void* __restrict__ bk, const void* __restrict__ bv,
                    const void* __restrict__ bo, uint16_t* __restrict__ dst,
                    const int* __restrict__ flagp)
{
    const bool f32in = (*flagp != 0);
    const size_t M4 = 4194304, M1 = 1048576;
    const size_t e = ((size_t)blockIdx.x * 256 + threadIdx.x) * 8;
    const void* src; size_t off;
    if      (e < M4)                 { src = x;  off = e; }
    else if (e < M4 + M1)            { src = Wq; off = e - M4; }
    else if (e < M4 + 2*M1)          { src = Wk; off = e - M4 - M1; }
    else if (e < M4 + 3*M1)          { src = Wv; off = e - M4 - 2*M1; }
    else if (e < M4 + 4*M1)          { src = Wo; off = e - M4 - 3*M1; }
    else if (e < M4 + 4*M1 + 1024)   { src = bq; off = e - M4 - 4*M1; }
    else if (e < M4 + 4*M1 + 2048)   { src = bk; off = e - M4 - 4*M1 - 1024; }
    else if (e < M4 + 4*M1 + 3072)   { src = bv; off = e - M4 - 4*M1 - 2048; }
    else                             { src = bo; off = e - M4 - 4*M1 - 3072; }
    if (f32in) {
        const float4 a = *(const float4*)((const float*)src + off);
        const float4 b = *(const float4*)((const float*)src + off + 4);
        uint4 o;
        o.x = (uint32_t)f2bf(a.x) | ((uint32_t)f2bf(a.y) << 16);
        o.y = (uint32_t)f2bf(a.z) | ((uint32_t)f2bf(a.w) << 16);
        o.z = (uint32_t)f2bf(b.x) | ((uint32_t)f2bf(b.y) << 16);
        o.w = (uint32_t)f2bf(b.z) | ((uint32_t)f2bf(b.w) << 16);
        *(uint4*)(dst + e) = o;
    } else {
        *(uint4*)(dst + e) = *(const uint4*)((const uint16_t*)src + off);
    }
}

// ============================================================
// Fused QKV MFMA GEMM v2: 2-phase double-buffered staging (same
// transformation that took attn 77.5 -> 55 us in R3). Prologue stages
// buf0; each double-iter prefetches the next K-slab BEFORE computing the
// current one -> the barrier's vmcnt(0) drain lands a full compute-phase
// after issue; 1 barrier per K-step (was 2). Arithmetic order unchanged.
// Q output PRESCALED by 0.125*log2(e) for exp2 softmax.
// ============================================================
#define QKV_STEP(AS, BS)                                                       \
  do {                                                                         \
    bf16x8 af[4], bfr[4];                                                      \
    _Pragma("unroll")                                                          \
    for (int t4 = 0; t4 < 4; ++t4) {                                           \
        af[t4]  = ld_frag(&(AS)[(wm + t4 * 16 + ln) * 32 + quad * 8]);         \
        bfr[t4] = ld_frag(&(BS)[(wn + t4 * 16 + ln) * 32 + quad * 8]);         \
    }                                                                          \
    _Pragma("unroll")                                                          \
    for (int ti = 0; ti < 4; ++ti)                                             \
      _Pragma("unroll")                                                        \
      for (int tj = 0; tj < 4; ++tj)                                           \
        acc[ti][tj] = MFMA16(af[ti], bfr[tj], acc[ti][tj]);                    \
  } while (0)

__global__ __launch_bounds__(256)
void gemm_qkv(const uint16_t* __restrict__ xc, const uint16_t* __restrict__ Wqkv,
              const uint16_t* __restrict__ bqkv,
              uint16_t* __restrict__ Qw, uint16_t* __restrict__ Kw,
              uint16_t* __restrict__ Vt)
{
    __shared__ uint16_t As[2][128 * 32];
    __shared__ uint16_t Bs[2][128 * 32];
    const int tid = threadIdx.x, bx = blockIdx.x;
    const int lane = tid & 63, wave = tid >> 6;
    const int ln = lane & 15, quad = lane >> 4;
    const int wm = (wave & 1) * 64, wn = (wave >> 1) * 64;

    const uint16_t *Ab, *Bb;
    int bm, bn, vor;
    if (bx < 512) {
        vor = 0; bm = (bx >> 4) * 128; bn = (bx & 15) * 128;
        Ab = xc + (size_t)bm * DM;  Bb = Wqkv + (size_t)bn * DM;
    } else {
        vor = 1; const int b2 = bx - 512; bm = (b2 >> 5) * 128; bn = (b2 & 31) * 128;
        Ab = Wqkv + (size_t)(2048 + bm) * DM;  Bb = xc + (size_t)bn * DM;
    }

    f32x4 acc[4][4];
    #pragma unroll
    for (int i = 0; i < 4; ++i)
        #pragma unroll
        for (int j = 0; j < 4; ++j) acc[i][j] = (f32x4){0.f, 0.f, 0.f, 0.f};

    const int s0 = tid, s1 = 256 + tid;
    const uint16_t* ga0 = Ab + (size_t)(s0 >> 2) * DM + (s0 & 3) * 8;
    const uint16_t* ga1 = Ab + (size_t)(s1 >> 2) * DM + (s1 & 3) * 8;
    const uint16_t* gb0 = Bb + (size_t)(s0 >> 2) * DM + (s0 & 3) * 8;
    const uint16_t* gb1 = Bb + (size_t)(s1 >> 2) * DM + (s1 & 3) * 8;

    // prologue: stage k=0 slab into buf0
    gld16(ga0, &As[0][s0 * 8]);
    gld16(ga1, &As[0][s1 * 8]);
    gld16(gb0, &Bs[0][s0 * 8]);
    gld16(gb1, &Bs[0][s1 * 8]);
    __syncthreads();

    for (int t = 0; t < 16; ++t) {
        const int kB = t * 64 + 32;
        gld16(ga0 + kB, &As[1][s0 * 8]);
        gld16(ga1 + kB, &As[1][s1 * 8]);
        gld16(gb0 + kB, &Bs[1][s0 * 8]);
        gld16(gb1 + kB, &Bs[1][s1 * 8]);
        QKV_STEP(As[0], Bs[0]);
        __syncthreads();

        if (t < 15) {
            const int kA = t * 64 + 64;
            gld16(ga0 + kA, &As[0][s0 * 8]);
            gld16(ga1 + kA, &As[0][s1 * 8]);
            gld16(gb0 + kA, &Bs[0][s0 * 8]);
            gld16(gb1 + kA, &Bs[0][s1 * 8]);
        }
        QKV_STEP(As[1], Bs[1]);
        __syncthreads();
    }

    if (!vor) {
        #pragma unroll
        for (int tj = 0; tj < 4; ++tj) {
            const int c = bn + wn + tj * 16 + ln;
            const int mat = c >> 10, h = (c >> 6) & 15, hd = c & 63;
            uint16_t* dstp = mat ? Kw : Qw;
            const float scale = mat ? 1.0f : (0.125f * LOG2E);
            const float bb = bf1(bqkv[c]);
            #pragma unroll
            for (int ti = 0; ti < 4; ++ti)
                #pragma unroll
                for (int r = 0; r < 4; ++r) {
                    const int row = bm + wm + ti * 16 + quad * 4 + r;
                    const int b = row >> 11, s = row & 2047;
                    dstp[(((size_t)b * NH + h) * SEQ + s) * HD + hd] =
                        f2bf((acc[ti][tj][r] + bb) * scale);
                }
        }
    } else {
        #pragma unroll
        for (int ti = 0; ti < 4; ++ti)
            #pragma unroll
            for (int r = 0; r < 4; ++r) {
                const int f = bm + wm + ti * 16 + quad * 4 + r;
                const int h = f >> 6, hd = f & 63;
                const float bb = bf1(bqkv[2048 + f]);
                #pragma unroll
                for (int tj = 0; tj < 4; ++tj) {
                    const int t = bn + wn + tj * 16 + ln;
                    const int b = t >> 11, s = t & 2047;
                    Vt[(((size_t)b * NH + h) * HD + hd) * SEQ + s] = f2bf(acc[ti][tj][r] + bb);
                }
            }
    }
}

// ============================================================
// Output projection v2: same 2-phase double-buffer. 128x64 tiles,
// 512 blocks. out = Cw · Woc^T + bo.
// ============================================================
#define GO_STEP(AS, BS)                                                        \
  do {                                                                         \
    bf16x8 af[4], bfr[2];                                                      \
    _Pragma("unroll")                                                          \
    for (int t4 = 0; t4 < 4; ++t4)                                             \
        af[t4] = ld_frag(&(AS)[(wm + t4 * 16 + ln) * 32 + quad * 8]);          \
    _Pragma("unroll")                                                          \
    for (int t2 = 0; t2 < 2; ++t2)                                             \
        bfr[t2] = ld_frag(&(BS)[(wn + t2 * 16 + ln) * 32 + quad * 8]);         \
    _Pragma("unroll")                                                          \
    for (int ti = 0; ti < 4; ++ti)                                             \
      _Pragma("unroll")                                                        \
      for (int tj = 0; tj < 2; ++tj)                                           \
        acc[ti][tj] = MFMA16(af[ti], bfr[tj], acc[ti][tj]);                    \
  } while (0)

__global__ __launch_bounds__(256)
void gemm_out(const uint16_t* __restrict__ Cw, const uint16_t* __restrict__ Woc,
              const uint16_t* __restrict__ boc, void* __restrict__ out,
              const int* __restrict__ flagp)
{
    __shared__ uint16_t As[2][128 * 32];
    __shared__ uint16_t Bs[2][64 * 32];
    const int tid = threadIdx.x, bx = blockIdx.x;
    const int lane = tid & 63, wave = tid >> 6;
    const int ln = lane & 15, quad = lane >> 4;
    const int wm = (wave & 1) * 64, wn = (wave >> 1) * 32;
    const int bm = (bx >> 4) * 128, bn = (bx & 15) * 64;
    const uint16_t* Ab = Cw + (size_t)bm * DM;
    const uint16_t* Bb = Woc + (size_t)bn * DM;

    f32x4 acc[4][2];
    #pragma unroll
    for (int i = 0; i < 4; ++i)
        #pragma unroll
        for (int j = 0; j < 2; ++j) acc[i][j] = (f32x4){0.f, 0.f, 0.f, 0.f};

    const int s0 = tid, s1 = 256 + tid;
    const uint16_t* ga0 = Ab + (size_t)(s0 >> 2) * DM + (s0 & 3) * 8;
    const uint16_t* ga1 = Ab + (size_t)(s1 >> 2) * DM + (s1 & 3) * 8;
    const uint16_t* gb0 = Bb + (size_t)(s0 >> 2) * DM + (s0 & 3) * 8;

    // prologue: stage k=0 slab into buf0
    gld16(ga0, &As[0][s0 * 8]);
    gld16(ga1, &As[0][s1 * 8]);
    gld16(gb0, &Bs[0][s0 * 8]);
    __syncthreads();

    for (int t = 0; t < 16; ++t) {
        const int kB = t * 64 + 32;
        gld16(ga0 + kB, &As[1][s0 * 8]);
        gld16(ga1 + kB, &As[1][s1 * 8]);
        gld16(gb0 + kB, &Bs[1][s0 * 8]);
        GO_STEP(As[0], Bs[0]);
        __syncthreads();

        if (t < 15) {
            const int kA = t * 64 + 64;
            gld16(ga0 + kA, &As[0][s0 * 8]);
            gld16(ga1 + kA, &As[0][s1 * 8]);
            gld16(gb0 + kA, &Bs[0][s0 * 8]);
        }
        GO_STEP(As[1], Bs[1]);
        __syncthreads();
    }

    const bool f32o = (*flagp != 0);
    #pragma unroll
    for (int tj = 0; tj < 2; ++tj) {
        const int c = bn + wn + tj * 16 + ln;
        const float bb = bf1(boc[c]);
        #pragma unroll
        for (int ti = 0; ti < 4; ++ti)
            #pragma unroll
            for (int r = 0; r < 4; ++r) {
                const int row = bm + wm + ti * 16 + quad * 4 + r;
                const float v = acc[ti][tj][r] + bb;
                if (f32o) ((float*)out)[(size_t)row * DM + c] = v;
                else      ((uint16_t*)out)[(size_t)row * DM + c] = f2bf(v);
            }
    }
}

// ============================================================
// Flash-style MFMA attention v13 (PROVEN GREEN @51us, reverted from the
// failed v14 KV-split): MFMA32 swapped QK^T, in-register softmax via
// cvt_pk + builtin permlane32_swap, l via ones-MFMA, diag bias in-reg.
// v14's in-block split-merge failed absmax 0.948 (bug not localized
// after full audit; arc abandoned). This copy is byte-identical to R7.
// ============================================================
#define P_BUILD(SA, PA_LO, PA_HI)                                              \
  do {                                                                         \
    uint32_t c0_ = cvt_pk_bf16((SA)[0], (SA)[1]);                              \
    uint32_t c1_ = cvt_pk_bf16((SA)[2], (SA)[3]);                              \
    uint32_t c2_ = cvt_pk_bf16((SA)[4], (SA)[5]);                              \
    uint32_t c3_ = cvt_pk_bf16((SA)[6], (SA)[7]);                              \
    uint32_t c4_ = cvt_pk_bf16((SA)[8], (SA)[9]);                              \
    uint32_t c5_ = cvt_pk_bf16((SA)[10], (SA)[11]);                            \
    uint32_t c6_ = cvt_pk_bf16((SA)[12], (SA)[13]);                            \
    uint32_t c7_ = cvt_pk_bf16((SA)[14], (SA)[15]);                            \
    pl32(c0_, c2_); pl32(c1_, c3_);                                            \
    pl32(c4_, c6_); pl32(c5_, c7_);                                            \
    union { uint32_t u[4]; bf16x8 f; } lo_, hi_;                               \
    lo_.u[0] = c0_; lo_.u[1] = c1_; lo_.u[2] = c2_; lo_.u[3] = c3_;            \
    hi_.u[0] = c4_; hi_.u[1] = c5_; hi_.u[2] = c6_; hi_.u[3] = c7_;            \
    (PA_LO) = lo_.f; (PA_HI) = hi_.f;                                          \
  } while (0)

#define ATTN_COMPUTE(K0, KSB, VSB)                                             \
  do {                                                                         \
    const int mode_ = ((K0) >= q0 + 256) ? 0 : (((K0) + 192 <= q0) ? 2 : 1);   \
    bf16x8 kf_[2][4], vf_[2][4];                                               \
    _Pragma("unroll")                                                          \
    for (int kb = 0; kb < 2; ++kb)                                             \
      _Pragma("unroll")                                                        \
      for (int ds = 0; ds < 4; ++ds)                                           \
        kf_[kb][ds] = ld_frag((KSB) + kfo[kb][ds]);                            \
    _Pragma("unroll")                                                          \
    for (int db = 0; db < 2; ++db)                                             \
      _Pragma("unroll")                                                        \
      for (int kc = 0; kc < 4; ++kc)                                           \
        vf_[db][kc] = ld_frag((VSB) + vfo[db][kc]);                            \
    f32x16 sa0, sa1;                                                           \
    {                                                                          \
      const float binit_ = (mode_ == 0) ? bneg : ((mode_ == 2) ? bpos : 0.f);  \
      _Pragma("unroll")                                                        \
      for (int r = 0; r < 16; ++r) { sa0[r] = binit_; sa1[r] = binit_; }       \
    }                                                                          \
    _Pragma("unroll")                                                          \
    for (int ds = 0; ds < 4; ++ds) {                                           \
      sa0 = MFMA32(kf_[0][ds], qb[ds], sa0);                                   \
      sa1 = MFMA32(kf_[1][ds], qb[ds], sa1);                                   \
    }                                                                          \
    if (mode_ == 1) {                                                          \
      const int iq0_ = q0 + wave * 32 + l31 + 128 - (K0) - 4 * hi;             \
      _Pragma("unroll")                                                        \
      for (int r = 0; r < 16; ++r) {                                           \
        const int ko_ = (r & 3) + 8 * (r >> 2);                                \
        const int x0_ = max(0, min(256, iq0_ - ko_));                          \
        const int x1_ = max(0, min(256, iq0_ - 32 - ko_));                     \
        sa0[r] += bias_s[x0_];                                                 \
        sa1[r] += bias_s[x1_];                                                 \
      }                                                                        \
    }                                                                          \
    _Pragma("unroll")                                                          \
    for (int r = 0; r < 16; ++r) {                                             \
      sa0[r] = __builtin_amdgcn_exp2f(sa0[r]);                                 \
      sa1[r] = __builtin_amdgcn_exp2f(sa1[r]);                                 \
    }                                                                          \
    bf16x8 pa_[4];                                                             \
    P_BUILD(sa0, pa_[0], pa_[1]);                                              \
    P_BUILD(sa1, pa_[2], pa_[3]);                                              \
    _Pragma("unroll")                                                          \
    for (int kc = 0; kc < 4; ++kc) {                                           \
      lf    = MFMA32(pa_[kc], onef, lf);                                       \
      o2[0] = MFMA32(pa_[kc], vf_[0][kc], o2[0]);                              \
      o2[1] = MFMA32(pa_[kc], vf_[1][kc], o2[1]);                              \
    }                                                                          \
  } while (0)

__global__ __launch_bounds__(256, 2)
void attn_mfma(const uint16_t* __restrict__ Q, const uint16_t* __restrict__ K,
               const uint16_t* __restrict__ Vt, const void* __restrict__ rel,
               uint16_t* __restrict__ ctx, const int* __restrict__ flagp)
{
    __shared__ alignas(16) uint16_t Ks[2][64 * 64];   // [buf][key][d], swizzled, 16 KB
    __shared__ alignas(16) uint16_t Vls[2][64 * 64];  // [buf][d][key], swizzled, 16 KB
    __shared__ float bias_s[NBUCKET];                 // bias*log2e - C8

    const bool f32in = (*flagp != 0);
    const int tid = threadIdx.x, wave = tid >> 6, lane = tid & 63;
    const int l31 = lane & 31, hi = lane >> 5;

    const int blk = blockIdx.x;                         // 512 blocks
    const int bh = (blk & 7) * 4 + ((blk >> 3) & 3);    // XCD-aware bh spread
    const int qt = blk >> 5;                            // 16 q-tiles of 128 rows
    const int b = bh >> 4, h = bh & 15;
    const int q0 = qt * 128;

    const float C8 = 8.0f * LOG2E;   // fixed-max shift (in exp2 domain)
    for (int i = tid; i < NBUCKET; i += 256) {
        const float bv = f32in ? ((const float*)rel)[i * NH + h]
                               : bf1(((const uint16_t*)rel)[i * NH + h]);
        bias_s[i] = bv * LOG2E - C8;
    }

    // Q B-frags (32x32x16 B-layout): lane holds col q = l31, k = hi*8+j
    bf16x8 qb[4];
    {
        const uint16_t* qp = Q + ((size_t)bh * SEQ + q0 + wave * 32 + l31) * HD;
        #pragma unroll
        for (int ds = 0; ds < 4; ++ds)
            qb[ds] = ld_frag(qp + ds * 16 + hi * 8);
    }

    // ones B-frag for l = P · 1 (reads the same bf16 pa frags as PV)
    union { uint4 u; bf16x8 f; } onec;
    onec.u = (uint4){0x3F803F80u, 0x3F803F80u, 0x3F803F80u, 0x3F803F80u};
    const bf16x8 onef = onec.f;

    f32x16 o2[2], lf;
    #pragma unroll
    for (int r = 0; r < 16; ++r) { o2[0][r] = 0.f; o2[1][r] = 0.f; lf[r] = 0.f; }

    // ---- staging: 256 threads x 2 segments x 16 B = one 64x128B tile ----
    const int s0_ = tid, s1_ = tid + 256;
    const int r0_ = s0_ >> 3, c0s_ = (s0_ & 7) ^ (r0_ & 7);
    const int r1_ = s1_ >> 3, c1s_ = (s1_ & 7) ^ (r1_ & 7);
    const int koff0 = r0_ * HD + c0s_ * 8,  koff1 = r1_ * HD + c1s_ * 8;
    const int voff0 = r0_ * SEQ + c0s_ * 8, voff1 = r1_ * SEQ + c1s_ * 8;
    uint16_t* const kd00 = &Ks[0][s0_ * 8];
    uint16_t* const kd01 = &Ks[0][s1_ * 8];
    uint16_t* const kd10 = &Ks[1][s0_ * 8];
    uint16_t* const kd11 = &Ks[1][s1_ * 8];
    uint16_t* const vd00 = &Vls[0][s0_ * 8];
    uint16_t* const vd01 = &Vls[0][s1_ * 8];
    uint16_t* const vd10 = &Vls[1][s0_ * 8];
    uint16_t* const vd11 = &Vls[1][s1_ * 8];

    const uint16_t* kg = K  + (size_t)bh * SEQ * HD;   // +64*HD per tile
    const uint16_t* vg = Vt + (size_t)bh * HD * SEQ;   // +64 per tile

    // ---- k0-invariant LDS frag offsets (row&7 == l31&7 for both) ----
    const int swz = l31 & 7;
    int kfo[2][4], vfo[2][4];
    #pragma unroll
    for (int kb = 0; kb < 2; ++kb)
        #pragma unroll
        for (int ds = 0; ds < 4; ++ds)
            kfo[kb][ds] = (kb * 32 + l31) * 64 + ((ds * 2 + hi) ^ swz) * 8;
    #pragma unroll
    for (int db = 0; db < 2; ++db)
        #pragma unroll
        for (int kc = 0; kc < 4; ++kc)
            vfo[db][kc] = (db * 32 + l31) * 64 + ((kc * 2 + hi) ^ swz) * 8;

    // ---- prologue: stage tile 0 into buf0 ----
    gld16(kg + koff0, kd00); gld16(kg + koff1, kd01);
    gld16(vg + voff0, vd00); gld16(vg + voff1, vd01);
    kg += 64 * HD; vg += 64;
    __syncthreads();   // drains stage-0 + bias_s fill
    const float bneg = bias_s[0], bpos = bias_s[256];

    // ---- main loop: 16 double-iters, 1 barrier per k-tile ----
    for (int t = 0; t < 16; ++t) {
        // phase A: tile 2t in buf0; prefetch tile 2t+1 -> buf1
        gld16(kg + koff0, kd10); gld16(kg + koff1, kd11);
        gld16(vg + voff0, vd10); gld16(vg + voff1, vd11);
        kg += 64 * HD; vg += 64;
        ATTN_COMPUTE(t * 128, &Ks[0][0], &Vls[0][0]);
        __syncthreads();   // vmcnt(0) drain lands ~full phase after issue

        // phase B: tile 2t+1 in buf1; prefetch tile 2t+2 -> buf0
        if (t < 15) {
            gld16(kg + koff0, kd00); gld16(kg + koff1, kd01);
            gld16(vg + voff0, vd00); gld16(vg + voff1, vd01);
            kg += 64 * HD; vg += 64;
        }
        ATTN_COMPUTE(t * 128 + 64, &Ks[1][0], &Vls[1][0]);
        __syncthreads();
    }

    // ---- epilogue: lf[r] and o2[db][r] share the q=crow(r,hi) layout ----
    #pragma unroll
    for (int r = 0; r < 16; ++r) {
        const float inv = 1.0f / lf[r];
        const int qq = q0 + wave * 32 + (r & 3) + 8 * (r >> 2) + 4 * hi;
        #pragma unroll
        for (int db = 0; db < 2; ++db)
            ctx[(((size_t)b * SEQ + qq) * NH + h) * HD + db * 32 + l31] =
                f2bf(o2[db][r] * inv);
    }
}

// ============================================================
extern "C" void kernel_launch(void* const* d_in, const int* in_sizes, int n_in,
                              void* d_out, int out_size, void* d_ws, size_t ws_size,
                              hipStream_t stream)
{
    const void* x   = d_in[0];
    const void* Wq  = d_in[1];
    const void* bq  = d_in[2];
    const void* Wk  = d_in[3];
    const void* bk  = d_in[4];
    const void* Wv  = d_in[5];
    const void* bv  = d_in[6];
    const void* Wo  = d_in[7];
    const void* bo  = d_in[8];
    const void* rel = d_in[9];

    const size_t M4 = 4194304, M1 = 1048576;
    uint16_t* ws16 = (uint16_t*)d_ws;
    uint16_t* xc   = ws16;                    // 4M; reused as Cw after QKV GEMM
    uint16_t* Wqkv = ws16 + M4;               // 3M  [Wq;Wk;Wv]
    uint16_t* Woc  = ws16 + M4 + 3 * M1;      // 1M
    uint16_t* bqkv = ws16 + M4 + 4 * M1;      // 3072 [bq;bk;bv]
    uint16_t* boc  = bqkv + 3072;             // 1024
    uint16_t* Qw   = ws16 + M4 + 4 * M1 + 8192;
    uint16_t* Kw   = Qw + M4;
    uint16_t* Vt   = Kw + M4;
    int* flag = (int*)(Vt + M4);
    uint16_t* Cw = xc;   // overlay: xc dead after gemm_qkv

    sniff_kernel<<<1, 64, 0, stream>>>((const uint16_t*)x, flag);
    convert_kernel<<<4098, 256, 0, stream>>>(x, Wq, Wk, Wv, Wo, bq, bk, bv, bo,
                                             ws16, flag);
    gemm_qkv<<<768, 256, 0, stream>>>(xc, Wqkv, bqkv, Qw, Kw, Vt);
    attn_mfma<<<512, 256, 0, stream>>>(Qw, Kw, Vt, rel, Cw, flag);
    gemm_out<<<512, 256, 0, stream>>>(Cw, Woc, boc, d_out, flag);
}

// Round 10
// 205.771 us; speedup vs baseline: 1.0104x; 1.0104x over previous
//
#include <hip/hip_runtime.h>
#include <hip/hip_bf16.h>
#include <cstdint>
#include <cstddef>

#define DEVI __device__ __forceinline__

static constexpr int SEQ = 2048;
static constexpr int DM  = 1024;
static constexpr int NH  = 16;
static constexpr int HD  = 64;
static constexpr int NTOK = 2 * SEQ;
static constexpr int NBUCKET = 257;
static constexpr float LOG2E = 1.44269504088896f;

typedef __attribute__((ext_vector_type(8))) short bf16x8;
typedef __attribute__((ext_vector_type(4))) float f32x4;
typedef __attribute__((ext_vector_type(16))) float f32x16;
typedef __attribute__((ext_vector_type(2))) unsigned int uint32x2;
#define MFMA16(a, b, c) __builtin_amdgcn_mfma_f32_16x16x32_bf16((a), (b), (c), 0, 0, 0)
#define MFMA32(a, b, c) __builtin_amdgcn_mfma_f32_32x32x16_bf16((a), (b), (c), 0, 0, 0)

DEVI float bf1(uint16_t u)  { return __uint_as_float(((uint32_t)u) << 16); }
DEVI uint16_t f2bf(float f) {
    uint32_t x = __float_as_uint(f);
    x += 0x7fffu + ((x >> 16) & 1u);   // RTNE
    return (uint16_t)(x >> 16);
}
DEVI bf16x8 ld_frag(const uint16_t* p) {
    union { uint4 u; bf16x8 f; } c;
    c.u = *(const uint4*)p;
    return c.f;
}
DEVI void gld16(const uint16_t* g, uint16_t* l) {
    __builtin_amdgcn_global_load_lds(
        (const __attribute__((address_space(1))) uint32_t*)g,
        (__attribute__((address_space(3))) uint32_t*)l, 16, 0, 0);
}
// Guide-verified T12 primitives (proven green in v13).
DEVI uint32_t cvt_pk_bf16(float lo, float hi) {
    uint32_t r;
    asm("v_cvt_pk_bf16_f32 %0, %1, %2" : "=v"(r) : "v"(lo), "v"(hi));
    return r;
}
DEVI void pl32(uint32_t &a, uint32_t &b) {
    const uint32x2 r = __builtin_amdgcn_permlane32_swap(a, b, false, false);
    a = r[0]; b = r[1];
}

// ============================================================
// convert v2: sniff MERGED in (one fewer kernel + serial gap).
// Each block self-computes the dtype flag from x[0:512] (1 KB, L2-hit
// after the first block); block 0 publishes it for attn/gemm_out.
// ============================================================
__global__ __launch_bounds__(256)
void convert_kernel(const void* __restrict__ x, const void* __restrict__ Wq,
                    const void* __restrict__ Wk, const void* __restrict__ Wv,
                    const void* __restrict__ Wo, const void* __restrict__ bq,
                    const void* __restrict__ bk, const void* __restrict__ bv,
                    const void* __restrict__ bo, uint16_t* __restrict__ dst,
                    int* __restrict__ flag_out)
{
    __shared__ int f32s;
    if (threadIdx.x == 0) f32s = 0;
    __syncthreads();
    int bad = 0;
    for (int i = threadIdx.x; i < 512; i += 256) {
        const float v = bf1(((const uint16_t*)x)[i]);
        if (!(fabsf(v) < 64.0f)) bad = 1;
    }
    if (bad) f32s = 1;
    __syncthreads();
    const bool f32in = (f32s != 0);
    if (blockIdx.x == 0 && threadIdx.x == 0) *flag_out = f32in ? 1 : 0;

    const size_t M4 = 4194304, M1 = 1048576;
    const size_t e = ((size_t)blockIdx.x * 256 + threadIdx.x) * 8;
    const void* src; size_t off;
    if      (e < M4)                 { src = x;  off = e; }
    else if (e < M4 + M1)            { src = Wq; off = e - M4; }
    else if (e < M4 + 2*M1)          { src = Wk; off = e - M4 - M1; }
    else if (e < M4 + 3*M1)          { src = Wv; off = e - M4 - 2*M1; }
    else if (e < M4 + 4*M1)          { src = Wo; off = e - M4 - 3*M1; }
    else if (e < M4 + 4*M1 + 1024)   { src = bq; off = e - M4 - 4*M1; }
    else if (e < M4 + 4*M1 + 2048)   { src = bk; off = e - M4 - 4*M1 - 1024; }
    else if (e < M4 + 4*M1 + 3072)   { src = bv; off = e - M4 - 4*M1 - 2048; }
    else                             { src = bo; off = e - M4 - 4*M1 - 3072; }
    if (f32in) {
        const float4 a = *(const float4*)((const float*)src + off);
        const float4 b = *(const float4*)((const float*)src + off + 4);
        uint4 o;
        o.x = (uint32_t)f2bf(a.x) | ((uint32_t)f2bf(a.y) << 16);
        o.y = (uint32_t)f2bf(a.z) | ((uint32_t)f2bf(a.w) << 16);
        o.z = (uint32_t)f2bf(b.x) | ((uint32_t)f2bf(b.y) << 16);
        o.w = (uint32_t)f2bf(b.z) | ((uint32_t)f2bf(b.w) << 16);
        *(uint4*)(dst + e) = o;
    } else {
        *(uint4*)(dst + e) = *(const uint4*)((const uint16_t*)src + off);
    }
}

// ============================================================
// Fused QKV MFMA GEMM v2 (2-phase dbuf; R9 measured ~neutral, kept).
// Q output PRESCALED by 0.125*log2(e) for exp2 softmax.
// ============================================================
#define QKV_STEP(AS, BS)                                                       \
  do {                                                                         \
    bf16x8 af[4], bfr[4];                                                      \
    _Pragma("unroll")                                                          \
    for (int t4 = 0; t4 < 4; ++t4) {                                           \
        af[t4]  = ld_frag(&(AS)[(wm + t4 * 16 + ln) * 32 + quad * 8]);         \
        bfr[t4] = ld_frag(&(BS)[(wn + t4 * 16 + ln) * 32 + quad * 8]);         \
    }                                                                          \
    _Pragma("unroll")                                                          \
    for (int ti = 0; ti < 4; ++ti)                                             \
      _Pragma("unroll")                                                        \
      for (int tj = 0; tj < 4; ++tj)                                           \
        acc[ti][tj] = MFMA16(af[ti], bfr[tj], acc[ti][tj]);                    \
  } while (0)

__global__ __launch_bounds__(256)
void gemm_qkv(const uint16_t* __restrict__ xc, const uint16_t* __restrict__ Wqkv,
              const uint16_t* __restrict__ bqkv,
              uint16_t* __restrict__ Qw, uint16_t* __restrict__ Kw,
              uint16_t* __restrict__ Vt)
{
    __shared__ uint16_t As[2][128 * 32];
    __shared__ uint16_t Bs[2][128 * 32];
    const int tid = threadIdx.x, bx = blockIdx.x;
    const int lane = tid & 63, wave = tid >> 6;
    const int ln = lane & 15, quad = lane >> 4;
    const int wm = (wave & 1) * 64, wn = (wave >> 1) * 64;

    const uint16_t *Ab, *Bb;
    int bm, bn, vor;
    if (bx < 512) {
        vor = 0; bm = (bx >> 4) * 128; bn = (bx & 15) * 128;
        Ab = xc + (size_t)bm * DM;  Bb = Wqkv + (size_t)bn * DM;
    } else {
        vor = 1; const int b2 = bx - 512; bm = (b2 >> 5) * 128; bn = (b2 & 31) * 128;
        Ab = Wqkv + (size_t)(2048 + bm) * DM;  Bb = xc + (size_t)bn * DM;
    }

    f32x4 acc[4][4];
    #pragma unroll
    for (int i = 0; i < 4; ++i)
        #pragma unroll
        for (int j = 0; j < 4; ++j) acc[i][j] = (f32x4){0.f, 0.f, 0.f, 0.f};

    const int s0 = tid, s1 = 256 + tid;
    const uint16_t* ga0 = Ab + (size_t)(s0 >> 2) * DM + (s0 & 3) * 8;
    const uint16_t* ga1 = Ab + (size_t)(s1 >> 2) * DM + (s1 & 3) * 8;
    const uint16_t* gb0 = Bb + (size_t)(s0 >> 2) * DM + (s0 & 3) * 8;
    const uint16_t* gb1 = Bb + (size_t)(s1 >> 2) * DM + (s1 & 3) * 8;

    gld16(ga0, &As[0][s0 * 8]);
    gld16(ga1, &As[0][s1 * 8]);
    gld16(gb0, &Bs[0][s0 * 8]);
    gld16(gb1, &Bs[0][s1 * 8]);
    __syncthreads();

    for (int t = 0; t < 16; ++t) {
        const int kB = t * 64 + 32;
        gld16(ga0 + kB, &As[1][s0 * 8]);
        gld16(ga1 + kB, &As[1][s1 * 8]);
        gld16(gb0 + kB, &Bs[1][s0 * 8]);
        gld16(gb1 + kB, &Bs[1][s1 * 8]);
        QKV_STEP(As[0], Bs[0]);
        __syncthreads();

        if (t < 15) {
            const int kA = t * 64 + 64;
            gld16(ga0 + kA, &As[0][s0 * 8]);
            gld16(ga1 + kA, &As[0][s1 * 8]);
            gld16(gb0 + kA, &Bs[0][s0 * 8]);
            gld16(gb1 + kA, &Bs[0][s1 * 8]);
        }
        QKV_STEP(As[1], Bs[1]);
        __syncthreads();
    }

    if (!vor) {
        #pragma unroll
        for (int tj = 0; tj < 4; ++tj) {
            const int c = bn + wn + tj * 16 + ln;
            const int mat = c >> 10, h = (c >> 6) & 15, hd = c & 63;
            uint16_t* dstp = mat ? Kw : Qw;
            const float scale = mat ? 1.0f : (0.125f * LOG2E);
            const float bb = bf1(bqkv[c]);
            #pragma unroll
            for (int ti = 0; ti < 4; ++ti)
                #pragma unroll
                for (int r = 0; r < 4; ++r) {
                    const int row = bm + wm + ti * 16 + quad * 4 + r;
                    const int b = row >> 11, s = row & 2047;
                    dstp[(((size_t)b * NH + h) * SEQ + s) * HD + hd] =
                        f2bf((acc[ti][tj][r] + bb) * scale);
                }
        }
    } else {
        #pragma unroll
        for (int ti = 0; ti < 4; ++ti)
            #pragma unroll
            for (int r = 0; r < 4; ++r) {
                const int f = bm + wm + ti * 16 + quad * 4 + r;
                const int h = f >> 6, hd = f & 63;
                const float bb = bf1(bqkv[2048 + f]);
                #pragma unroll
                for (int tj = 0; tj < 4; ++tj) {
                    const int t = bn + wn + tj * 16 + ln;
                    const int b = t >> 11, s = t & 2047;
                    Vt[(((size_t)b * NH + h) * HD + hd) * SEQ + s] = f2bf(acc[ti][tj][r] + bb);
                }
            }
    }
}

// ============================================================
// Output projection v2 (2-phase dbuf, kept). out = Cw · Woc^T + bo.
// ============================================================
#define GO_STEP(AS, BS)                                                        \
  do {                                                                         \
    bf16x8 af[4], bfr[2];                                                      \
    _Pragma("unroll")                                                          \
    for (int t4 = 0; t4 < 4; ++t4)                                             \
        af[t4] = ld_frag(&(AS)[(wm + t4 * 16 + ln) * 32 + quad * 8]);          \
    _Pragma("unroll")                                                          \
    for (int t2 = 0; t2 < 2; ++t2)                                             \
        bfr[t2] = ld_frag(&(BS)[(wn + t2 * 16 + ln) * 32 + quad * 8]);         \
    _Pragma("unroll")                                                          \
    for (int ti = 0; ti < 4; ++ti)                                             \
      _Pragma("unroll")                                                        \
      for (int tj = 0; tj < 2; ++tj)                                           \
        acc[ti][tj] = MFMA16(af[ti], bfr[tj], acc[ti][tj]);                    \
  } while (0)

__global__ __launch_bounds__(256)
void gemm_out(const uint16_t* __restrict__ Cw, const uint16_t* __restrict__ Woc,
              const uint16_t* __restrict__ boc, void* __restrict__ out,
              const int* __restrict__ flagp)
{
    __shared__ uint16_t As[2][128 * 32];
    __shared__ uint16_t Bs[2][64 * 32];
    const int tid = threadIdx.x, bx = blockIdx.x;
    const int lane = tid & 63, wave = tid >> 6;
    const int ln = lane & 15, quad = lane >> 4;
    const int wm = (wave & 1) * 64, wn = (wave >> 1) * 32;
    const int bm = (bx >> 4) * 128, bn = (bx & 15) * 64;
    const uint16_t* Ab = Cw + (size_t)bm * DM;
    const uint16_t* Bb = Woc + (size_t)bn * DM;

    f32x4 acc[4][2];
    #pragma unroll
    for (int i = 0; i < 4; ++i)
        #pragma unroll
        for (int j = 0; j < 2; ++j) acc[i][j] = (f32x4){0.f, 0.f, 0.f, 0.f};

    const int s0 = tid, s1 = 256 + tid;
    const uint16_t* ga0 = Ab + (size_t)(s0 >> 2) * DM + (s0 & 3) * 8;
    const uint16_t* ga1 = Ab + (size_t)(s1 >> 2) * DM + (s1 & 3) * 8;
    const uint16_t* gb0 = Bb + (size_t)(s0 >> 2) * DM + (s0 & 3) * 8;

    gld16(ga0, &As[0][s0 * 8]);
    gld16(ga1, &As[0][s1 * 8]);
    gld16(gb0, &Bs[0][s0 * 8]);
    __syncthreads();

    for (int t = 0; t < 16; ++t) {
        const int kB = t * 64 + 32;
        gld16(ga0 + kB, &As[1][s0 * 8]);
        gld16(ga1 + kB, &As[1][s1 * 8]);
        gld16(gb0 + kB, &Bs[1][s0 * 8]);
        GO_STEP(As[0], Bs[0]);
        __syncthreads();

        if (t < 15) {
            const int kA = t * 64 + 64;
            gld16(ga0 + kA, &As[0][s0 * 8]);
            gld16(ga1 + kA, &As[0][s1 * 8]);
            gld16(gb0 + kA, &Bs[0][s0 * 8]);
        }
        GO_STEP(As[1], Bs[1]);
        __syncthreads();
    }

    const bool f32o = (*flagp != 0);
    #pragma unroll
    for (int tj = 0; tj < 2; ++tj) {
        const int c = bn + wn + tj * 16 + ln;
        const float bb = bf1(boc[c]);
        #pragma unroll
        for (int ti = 0; ti < 4; ++ti)
            #pragma unroll
            for (int r = 0; r < 4; ++r) {
                const int row = bm + wm + ti * 16 + quad * 4 + r;
                const float v = acc[ti][tj][r] + bb;
                if (f32o) ((float*)out)[(size_t)row * DM + c] = v;
                else      ((uint16_t*)out)[(size_t)row * DM + c] = f2bf(v);
            }
    }
}

// ============================================================
// Flash-style MFMA attention v15 = v13 (green math, untouched) with
// 128-key phases from a staged tile-PAIR:
//  * LDS: 2 pairs x 2 subtiles x (K,V) = 66.6 KB (still 2 blocks/CU,
//    occupancy unchanged — m132's occupancy trap avoided).
//  * Barriers 33 -> 17; the two 64-key pipelines per phase are
//    independent -> compiler interleaves (~2x ILP on the serial
//    ds_read->QK^T->exp2->cvt->PV chain that v13's counters showed as
//    the limit: MfmaUtil 33 / VALU 38 / Occ 17, nothing saturated).
//  * ATTN_COMPUTE byte-identical to v13 (mode/bias use absolute K0;
//    QBLK still 128 -> boundary conditions unchanged).
// ============================================================
#define P_BUILD(SA, PA_LO, PA_HI)                                              \
  do {                                                                         \
    uint32_t c0_ = cvt_pk_bf16((SA)[0], (SA)[1]);                              \
    uint32_t c1_ = cvt_pk_bf16((SA)[2], (SA)[3]);                              \
    uint32_t c2_ = cvt_pk_bf16((SA)[4], (SA)[5]);                              \
    uint32_t c3_ = cvt_pk_bf16((SA)[6], (SA)[7]);                              \
    uint32_t c4_ = cvt_pk_bf16((SA)[8], (SA)[9]);                              \
    uint32_t c5_ = cvt_pk_bf16((SA)[10], (SA)[11]);                            \
    uint32_t c6_ = cvt_pk_bf16((SA)[12], (SA)[13]);                            \
    uint32_t c7_ = cvt_pk_bf16((SA)[14], (SA)[15]);                            \
    pl32(c0_, c2_); pl32(c1_, c3_);                                            \
    pl32(c4_, c6_); pl32(c5_, c7_);                                            \
    union { uint32_t u[4]; bf16x8 f; } lo_, hi_;                               \
    lo_.u[0] = c0_; lo_.u[1] = c1_; lo_.u[2] = c2_; lo_.u[3] = c3_;            \
    hi_.u[0] = c4_; hi_.u[1] = c5_; hi_.u[2] = c6_; hi_.u[3] = c7_;            \
    (PA_LO) = lo_.f; (PA_HI) = hi_.f;                                          \
  } while (0)

#define ATTN_COMPUTE(K0, KSB, VSB)                                             \
  do {                                                                         \
    const int mode_ = ((K0) >= q0 + 256) ? 0 : (((K0) + 192 <= q0) ? 2 : 1);   \
    bf16x8 kf_[2][4], vf_[2][4];                                               \
    _Pragma("unroll")                                                          \
    for (int kb = 0; kb < 2; ++kb)                                             \
      _Pragma("unroll")                                                        \
      for (int ds = 0; ds < 4; ++ds)                                           \
        kf_[kb][ds] = ld_frag((KSB) + kfo[kb][ds]);                            \
    _Pragma("unroll")                                                          \
    for (int db = 0; db < 2; ++db)                                             \
      _Pragma("unroll")                                                        \
      for (int kc = 0; kc < 4; ++kc)                                           \
        vf_[db][kc] = ld_frag((VSB) + vfo[db][kc]);                            \
    f32x16 sa0, sa1;                                                           \
    {                                                                          \
      const float binit_ = (mode_ == 0) ? bneg : ((mode_ == 2) ? bpos : 0.f);  \
      _Pragma("unroll")                                                        \
      for (int r = 0; r < 16; ++r) { sa0[r] = binit_; sa1[r] = binit_; }       \
    }                                                                          \
    _Pragma("unroll")                                                          \
    for (int ds = 0; ds < 4; ++ds) {                                           \
      sa0 = MFMA32(kf_[0][ds], qb[ds], sa0);                                   \
      sa1 = MFMA32(kf_[1][ds], qb[ds], sa1);                                   \
    }                                                                          \
    if (mode_ == 1) {                                                          \
      const int iq0_ = q0 + wave * 32 + l31 + 128 - (K0) - 4 * hi;             \
      _Pragma("unroll")                                                        \
      for (int r = 0; r < 16; ++r) {                                           \
        const int ko_ = (r & 3) + 8 * (r >> 2);                                \
        const int x0_ = max(0, min(256, iq0_ - ko_));                          \
        const int x1_ = max(0, min(256, iq0_ - 32 - ko_));                     \
        sa0[r] += bias_s[x0_];                                                 \
        sa1[r] += bias_s[x1_];                                                 \
      }                                                                        \
    }                                                                          \
    _Pragma("unroll")                                                          \
    for (int r = 0; r < 16; ++r) {                                             \
      sa0[r] = __builtin_amdgcn_exp2f(sa0[r]);                                 \
      sa1[r] = __builtin_amdgcn_exp2f(sa1[r]);                                 \
    }                                                                          \
    bf16x8 pa_[4];                                                             \
    P_BUILD(sa0, pa_[0], pa_[1]);                                              \
    P_BUILD(sa1, pa_[2], pa_[3]);                                              \
    _Pragma("unroll")                                                          \
    for (int kc = 0; kc < 4; ++kc) {                                           \
      lf    = MFMA32(pa_[kc], onef, lf);                                       \
      o2[0] = MFMA32(pa_[kc], vf_[0][kc], o2[0]);                              \
      o2[1] = MFMA32(pa_[kc], vf_[1][kc], o2[1]);                              \
    }                                                                          \
  } while (0)

// Stage 64-key tile n (K and V) into pair p, subtile st.
#define STAGE_T(p, st, n)                                                      \
  do {                                                                         \
    gld16(Kb  + (size_t)(n) * 64 * HD + koff0, &Ks[p][st][s0_ * 8]);           \
    gld16(Kb  + (size_t)(n) * 64 * HD + koff1, &Ks[p][st][s1_ * 8]);           \
    gld16(Vtb + (n) * 64 + voff0,              &Vls[p][st][s0_ * 8]);          \
    gld16(Vtb + (n) * 64 + voff1,              &Vls[p][st][s1_ * 8]);          \
  } while (0)

__global__ __launch_bounds__(256, 2)
void attn_mfma(const uint16_t* __restrict__ Q, const uint16_t* __restrict__ K,
               const uint16_t* __restrict__ Vt, const void* __restrict__ rel,
               uint16_t* __restrict__ ctx, const int* __restrict__ flagp)
{
    __shared__ alignas(16) uint16_t Ks[2][2][4096];   // [pair][subtile], 32 KB
    __shared__ alignas(16) uint16_t Vls[2][2][4096];  // [pair][subtile], 32 KB
    __shared__ float bias_s[NBUCKET];                 // bias*log2e - C8

    const bool f32in = (*flagp != 0);
    const int tid = threadIdx.x, wave = tid >> 6, lane = tid & 63;
    const int l31 = lane & 31, hi = lane >> 5;

    const int blk = blockIdx.x;                         // 512 blocks
    const int bh = (blk & 7) * 4 + ((blk >> 3) & 3);    // XCD-aware bh spread
    const int qt = blk >> 5;                            // 16 q-tiles of 128 rows
    const int b = bh >> 4, h = bh & 15;
    const int q0 = qt * 128;

    const float C8 = 8.0f * LOG2E;   // fixed-max shift (in exp2 domain)
    for (int i = tid; i < NBUCKET; i += 256) {
        const float bv = f32in ? ((const float*)rel)[i * NH + h]
                               : bf1(((const uint16_t*)rel)[i * NH + h]);
        bias_s[i] = bv * LOG2E - C8;
    }

    // Q B-frags (32x32x16 B-layout): lane holds col q = l31, k = hi*8+j
    bf16x8 qb[4];
    {
        const uint16_t* qp = Q + ((size_t)bh * SEQ + q0 + wave * 32 + l31) * HD;
        #pragma unroll
        for (int ds = 0; ds < 4; ++ds)
            qb[ds] = ld_frag(qp + ds * 16 + hi * 8);
    }

    // ones B-frag for l = P · 1 (reads the same bf16 pa frags as PV)
    union { uint4 u; bf16x8 f; } onec;
    onec.u = (uint4){0x3F803F80u, 0x3F803F80u, 0x3F803F80u, 0x3F803F80u};
    const bf16x8 onef = onec.f;

    f32x16 o2[2], lf;
    #pragma unroll
    for (int r = 0; r < 16; ++r) { o2[0][r] = 0.f; o2[1][r] = 0.f; lf[r] = 0.f; }

    // ---- staging: 256 threads x 2 segments x 16 B = one 64x128B tile ----
    const int s0_ = tid, s1_ = tid + 256;
    const int r0_ = s0_ >> 3, c0s_ = (s0_ & 7) ^ (r0_ & 7);
    const int r1_ = s1_ >> 3, c1s_ = (s1_ & 7) ^ (r1_ & 7);
    const int koff0 = r0_ * HD + c0s_ * 8,  koff1 = r1_ * HD + c1s_ * 8;
    const int voff0 = r0_ * SEQ + c0s_ * 8, voff1 = r1_ * SEQ + c1s_ * 8;

    const uint16_t* Kb  = K  + (size_t)bh * SEQ * HD;
    const uint16_t* Vtb = Vt + (size_t)bh * HD * SEQ;

    // ---- k0-invariant LDS frag offsets (row&7 == l31&7 for both) ----
    const int swz = l31 & 7;
    int kfo[2][4], vfo[2][4];
    #pragma unroll
    for (int kb = 0; kb < 2; ++kb)
        #pragma unroll
        for (int ds = 0; ds < 4; ++ds)
            kfo[kb][ds] = (kb * 32 + l31) * 64 + ((ds * 2 + hi) ^ swz) * 8;
    #pragma unroll
    for (int db = 0; db < 2; ++db)
        #pragma unroll
        for (int kc = 0; kc < 4; ++kc)
            vfo[db][kc] = (db * 32 + l31) * 64 + ((kc * 2 + hi) ^ swz) * 8;

    // ---- prologue: stage tiles 0,1 into pair 0 ----
    STAGE_T(0, 0, 0);
    STAGE_T(0, 1, 1);
    __syncthreads();   // drains stage-0 + bias_s fill
    const float bneg = bias_s[0], bpos = bias_s[256];

    // ---- main loop: 16 iters x 128 keys, ONE barrier per iter ----
    for (int t = 0; t < 16; ++t) {
        const int p = t & 1, np = p ^ 1;
        if (t < 15) {                      // prefetch next pair (tiles 2t+2, 2t+3)
            STAGE_T(np, 0, 2 * t + 2);
            STAGE_T(np, 1, 2 * t + 3);
        }
        ATTN_COMPUTE(t * 128,      &Ks[p][0][0], &Vls[p][0][0]);
        ATTN_COMPUTE(t * 128 + 64, &Ks[p][1][0], &Vls[p][1][0]);
        __syncthreads();   // vmcnt(0) drain lands ~full 128-key phase after issue
    }

    // ---- epilogue: lf[r] and o2[db][r] share the q=crow(r,hi) layout ----
    #pragma unroll
    for (int r = 0; r < 16; ++r) {
        const float inv = 1.0f / lf[r];
        const int qq = q0 + wave * 32 + (r & 3) + 8 * (r >> 2) + 4 * hi;
        #pragma unroll
        for (int db = 0; db < 2; ++db)
            ctx[(((size_t)b * SEQ + qq) * NH + h) * HD + db * 32 + l31] =
                f2bf(o2[db][r] * inv);
    }
}

// ============================================================
extern "C" void kernel_launch(void* const* d_in, const int* in_sizes, int n_in,
                              void* d_out, int out_size, void* d_ws, size_t ws_size,
                              hipStream_t stream)
{
    const void* x   = d_in[0];
    const void* Wq  = d_in[1];
    const void* bq  = d_in[2];
    const void* Wk  = d_in[3];
    const void* bk  = d_in[4];
    const void* Wv  = d_in[5];
    const void* bv  = d_in[6];
    const void* Wo  = d_in[7];
    const void* bo  = d_in[8];
    const void* rel = d_in[9];

    const size_t M4 = 4194304, M1 = 1048576;
    uint16_t* ws16 = (uint16_t*)d_ws;
    uint16_t* xc   = ws16;                    // 4M; reused as Cw after QKV GEMM
    uint16_t* Wqkv = ws16 + M4;               // 3M  [Wq;Wk;Wv]
    uint16_t* Woc  = ws16 + M4 + 3 * M1;      // 1M
    uint16_t* bqkv = ws16 + M4 + 4 * M1;      // 3072 [bq;bk;bv]
    uint16_t* boc  = bqkv + 3072;             // 1024
    uint16_t* Qw   = ws16 + M4 + 4 * M1 + 8192;
    uint16_t* Kw   = Qw + M4;
    uint16_t* Vt   = Kw + M4;
    int* flag = (int*)(Vt + M4);
    uint16_t* Cw = xc;   // overlay: xc dead after gemm_qkv

    convert_kernel<<<4098, 256, 0, stream>>>(x, Wq, Wk, Wv, Wo, bq, bk, bv, bo,
                                             ws16, flag);
    gemm_qkv<<<768, 256, 0, stream>>>(xc, Wqkv, bqkv, Qw, Kw, Vt);
    attn_mfma<<<512, 256, 0, stream>>>(Qw, Kw, Vt, rel, Cw, flag);
    gemm_out<<<512, 256, 0, stream>>>(Cw, Woc, boc, d_out, flag);
}

// Round 13
// 204.724 us; speedup vs baseline: 1.0156x; 1.0051x over previous
//
#include <hip/hip_runtime.h>
#include <hip/hip_bf16.h>
#include <cstdint>
#include <cstddef>

#define DEVI __device__ __forceinline__

static constexpr int SEQ = 2048;
static constexpr int DM  = 1024;
static constexpr int NH  = 16;
static constexpr int HD  = 64;
static constexpr int NTOK = 2 * SEQ;
static constexpr int NBUCKET = 257;
static constexpr float LOG2E = 1.44269504088896f;

typedef __attribute__((ext_vector_type(8))) short bf16x8;
typedef __attribute__((ext_vector_type(4))) float f32x4;
typedef __attribute__((ext_vector_type(16))) float f32x16;
typedef __attribute__((ext_vector_type(2))) unsigned int uint32x2;
#define MFMA16(a, b, c) __builtin_amdgcn_mfma_f32_16x16x32_bf16((a), (b), (c), 0, 0, 0)
#define MFMA32(a, b, c) __builtin_amdgcn_mfma_f32_32x32x16_bf16((a), (b), (c), 0, 0, 0)

DEVI float bf1(uint16_t u)  { return __uint_as_float(((uint32_t)u) << 16); }
DEVI uint16_t f2bf(float f) {
    uint32_t x = __float_as_uint(f);
    x += 0x7fffu + ((x >> 16) & 1u);   // RTNE
    return (uint16_t)(x >> 16);
}
DEVI bf16x8 ld_frag(const uint16_t* p) {
    union { uint4 u; bf16x8 f; } c;
    c.u = *(const uint4*)p;
    return c.f;
}
DEVI void gld16(const uint16_t* g, uint16_t* l) {
    __builtin_amdgcn_global_load_lds(
        (const __attribute__((address_space(1))) uint32_t*)g,
        (__attribute__((address_space(3))) uint32_t*)l, 16, 0, 0);
}
// Guide-verified T12 primitives (proven green in v13).
DEVI uint32_t cvt_pk_bf16(float lo, float hi) {
    uint32_t r;
    asm("v_cvt_pk_bf16_f32 %0, %1, %2" : "=v"(r) : "v"(lo), "v"(hi));
    return r;
}
DEVI void pl32(uint32_t &a, uint32_t &b) {
    const uint32x2 r = __builtin_amdgcn_permlane32_swap(a, b, false, false);
    a = r[0]; b = r[1];
}

// ============================================================
// convert v2: sniff merged in (green in R10).
// ============================================================
__global__ __launch_bounds__(256)
void convert_kernel(const void* __restrict__ x, const void* __restrict__ Wq,
                    const void* __restrict__ Wk, const void* __restrict__ Wv,
                    const void* __restrict__ Wo, const void* __restrict__ bq,
                    const void* __restrict__ bk, const void* __restrict__ bv,
                    const void* __restrict__ bo, uint16_t* __restrict__ dst,
                    int* __restrict__ flag_out)
{
    __shared__ int f32s;
    if (threadIdx.x == 0) f32s = 0;
    __syncthreads();
    int bad = 0;
    for (int i = threadIdx.x; i < 512; i += 256) {
        const float v = bf1(((const uint16_t*)x)[i]);
        if (!(fabsf(v) < 64.0f)) bad = 1;
    }
    if (bad) f32s = 1;
    __syncthreads();
    const bool f32in = (f32s != 0);
    if (blockIdx.x == 0 && threadIdx.x == 0) *flag_out = f32in ? 1 : 0;

    const size_t M4 = 4194304, M1 = 1048576;
    const size_t e = ((size_t)blockIdx.x * 256 + threadIdx.x) * 8;
    const void* src; size_t off;
    if      (e < M4)                 { src = x;  off = e; }
    else if (e < M4 + M1)            { src = Wq; off = e - M4; }
    else if (e < M4 + 2*M1)          { src = Wk; off = e - M4 - M1; }
    else if (e < M4 + 3*M1)          { src = Wv; off = e - M4 - 2*M1; }
    else if (e < M4 + 4*M1)          { src = Wo; off = e - M4 - 3*M1; }
    else if (e < M4 + 4*M1 + 1024)   { src = bq; off = e - M4 - 4*M1; }
    else if (e < M4 + 4*M1 + 2048)   { src = bk; off = e - M4 - 4*M1 - 1024; }
    else if (e < M4 + 4*M1 + 3072)   { src = bv; off = e - M4 - 4*M1 - 2048; }
    else                             { src = bo; off = e - M4 - 4*M1 - 3072; }
    if (f32in) {
        const float4 a = *(const float4*)((const float*)src + off);
        const float4 b = *(const float4*)((const float*)src + off + 4);
        uint4 o;
        o.x = (uint32_t)f2bf(a.x) | ((uint32_t)f2bf(a.y) << 16);
        o.y = (uint32_t)f2bf(a.z) | ((uint32_t)f2bf(a.w) << 16);
        o.z = (uint32_t)f2bf(b.x) | ((uint32_t)f2bf(b.y) << 16);
        o.w = (uint32_t)f2bf(b.z) | ((uint32_t)f2bf(b.w) << 16);
        *(uint4*)(dst + e) = o;
    } else {
        *(uint4*)(dst + e) = *(const uint4*)((const uint16_t*)src + off);
    }
}

// ============================================================
// Fused QKV MFMA GEMM v2 (unchanged, green).
// ============================================================
#define QKV_STEP(AS, BS)                                                       \
  do {                                                                         \
    bf16x8 af[4], bfr[4];                                                      \
    _Pragma("unroll")                                                          \
    for (int t4 = 0; t4 < 4; ++t4) {                                           \
        af[t4]  = ld_frag(&(AS)[(wm + t4 * 16 + ln) * 32 + quad * 8]);         \
        bfr[t4] = ld_frag(&(BS)[(wn + t4 * 16 + ln) * 32 + quad * 8]);         \
    }                                                                          \
    _Pragma("unroll")                                                          \
    for (int ti = 0; ti < 4; ++ti)                                             \
      _Pragma("unroll")                                                        \
      for (int tj = 0; tj < 4; ++tj)                                           \
        acc[ti][tj] = MFMA16(af[ti], bfr[tj], acc[ti][tj]);                    \
  } while (0)

__global__ __launch_bounds__(256)
void gemm_qkv(const uint16_t* __restrict__ xc, const uint16_t* __restrict__ Wqkv,
              const uint16_t* __restrict__ bqkv,
              uint16_t* __restrict__ Qw, uint16_t* __restrict__ Kw,
              uint16_t* __restrict__ Vt)
{
    __shared__ uint16_t As[2][128 * 32];
    __shared__ uint16_t Bs[2][128 * 32];
    const int tid = threadIdx.x, bx = blockIdx.x;
    const int lane = tid & 63, wave = tid >> 6;
    const int ln = lane & 15, quad = lane >> 4;
    const int wm = (wave & 1) * 64, wn = (wave >> 1) * 64;

    const uint16_t *Ab, *Bb;
    int bm, bn, vor;
    if (bx < 512) {
        vor = 0; bm = (bx >> 4) * 128; bn = (bx & 15) * 128;
        Ab = xc + (size_t)bm * DM;  Bb = Wqkv + (size_t)bn * DM;
    } else {
        vor = 1; const int b2 = bx - 512; bm = (b2 >> 5) * 128; bn = (b2 & 31) * 128;
        Ab = Wqkv + (size_t)(2048 + bm) * DM;  Bb = xc + (size_t)bn * DM;
    }

    f32x4 acc[4][4];
    #pragma unroll
    for (int i = 0; i < 4; ++i)
        #pragma unroll
        for (int j = 0; j < 4; ++j) acc[i][j] = (f32x4){0.f, 0.f, 0.f, 0.f};

    const int s0 = tid, s1 = 256 + tid;
    const uint16_t* ga0 = Ab + (size_t)(s0 >> 2) * DM + (s0 & 3) * 8;
    const uint16_t* ga1 = Ab + (size_t)(s1 >> 2) * DM + (s1 & 3) * 8;
    const uint16_t* gb0 = Bb + (size_t)(s0 >> 2) * DM + (s0 & 3) * 8;
    const uint16_t* gb1 = Bb + (size_t)(s1 >> 2) * DM + (s1 & 3) * 8;

    gld16(ga0, &As[0][s0 * 8]);
    gld16(ga1, &As[0][s1 * 8]);
    gld16(gb0, &Bs[0][s0 * 8]);
    gld16(gb1, &Bs[0][s1 * 8]);
    __syncthreads();

    for (int t = 0; t < 16; ++t) {
        const int kB = t * 64 + 32;
        gld16(ga0 + kB, &As[1][s0 * 8]);
        gld16(ga1 + kB, &As[1][s1 * 8]);
        gld16(gb0 + kB, &Bs[1][s0 * 8]);
        gld16(gb1 + kB, &Bs[1][s1 * 8]);
        QKV_STEP(As[0], Bs[0]);
        __syncthreads();

        if (t < 15) {
            const int kA = t * 64 + 64;
            gld16(ga0 + kA, &As[0][s0 * 8]);
            gld16(ga1 + kA, &As[0][s1 * 8]);
            gld16(gb0 + kA, &Bs[0][s0 * 8]);
            gld16(gb1 + kA, &Bs[0][s1 * 8]);
        }
        QKV_STEP(As[1], Bs[1]);
        __syncthreads();
    }

    if (!vor) {
        #pragma unroll
        for (int tj = 0; tj < 4; ++tj) {
            const int c = bn + wn + tj * 16 + ln;
            const int mat = c >> 10, h = (c >> 6) & 15, hd = c & 63;
            uint16_t* dstp = mat ? Kw : Qw;
            const float scale = mat ? 1.0f : (0.125f * LOG2E);
            const float bb = bf1(bqkv[c]);
            #pragma unroll
            for (int ti = 0; ti < 4; ++ti)
                #pragma unroll
                for (int r = 0; r < 4; ++r) {
                    const int row = bm + wm + ti * 16 + quad * 4 + r;
                    const int b = row >> 11, s = row & 2047;
                    dstp[(((size_t)b * NH + h) * SEQ + s) * HD + hd] =
                        f2bf((acc[ti][tj][r] + bb) * scale);
                }
        }
    } else {
        #pragma unroll
        for (int ti = 0; ti < 4; ++ti)
            #pragma unroll
            for (int r = 0; r < 4; ++r) {
                const int f = bm + wm + ti * 16 + quad * 4 + r;
                const int h = f >> 6, hd = f & 63;
                const float bb = bf1(bqkv[2048 + f]);
                #pragma unroll
                for (int tj = 0; tj < 4; ++tj) {
                    const int t = bn + wn + tj * 16 + ln;
                    const int b = t >> 11, s = t & 2047;
                    Vt[(((size_t)b * NH + h) * HD + hd) * SEQ + s] = f2bf(acc[ti][tj][r] + bb);
                }
            }
    }
}

// ============================================================
// Output projection v2 (green R9/R10). out = Cw · Woc^T + bo.
// ============================================================
#define GO_STEP(AS, BS)                                                        \
  do {                                                                         \
    bf16x8 af[4], bfr[2];                                                      \
    _Pragma("unroll")                                                          \
    for (int t4 = 0; t4 < 4; ++t4)                                             \
        af[t4] = ld_frag(&(AS)[(wm + t4 * 16 + ln) * 32 + quad * 8]);          \
    _Pragma("unroll")                                                          \
    for (int t2 = 0; t2 < 2; ++t2)                                             \
        bfr[t2] = ld_frag(&(BS)[(wn + t2 * 16 + ln) * 32 + quad * 8]);         \
    _Pragma("unroll")                                                          \
    for (int ti = 0; ti < 4; ++ti)                                             \
      _Pragma("unroll")                                                        \
      for (int tj = 0; tj < 2; ++tj)                                           \
        acc[ti][tj] = MFMA16(af[ti], bfr[tj], acc[ti][tj]);                    \
  } while (0)

__global__ __launch_bounds__(256)
void gemm_out(const uint16_t* __restrict__ Cw, const uint16_t* __restrict__ Woc,
              const uint16_t* __restrict__ boc, void* __restrict__ out,
              const int* __restrict__ flagp)
{
    __shared__ uint16_t As[2][128 * 32];
    __shared__ uint16_t Bs[2][64 * 32];
    const int tid = threadIdx.x, bx = blockIdx.x;
    const int lane = tid & 63, wave = tid >> 6;
    const int ln = lane & 15, quad = lane >> 4;
    const int wm = (wave & 1) * 64, wn = (wave >> 1) * 32;
    const int bm = (bx >> 4) * 128, bn = (bx & 15) * 64;
    const uint16_t* Ab = Cw + (size_t)bm * DM;
    const uint16_t* Bb = Woc + (size_t)bn * DM;

    f32x4 acc[4][2];
    #pragma unroll
    for (int i = 0; i < 4; ++i)
        #pragma unroll
        for (int j = 0; j < 2; ++j) acc[i][j] = (f32x4){0.f, 0.f, 0.f, 0.f};

    const int s0 = tid, s1 = 256 + tid;
    const uint16_t* ga0 = Ab + (size_t)(s0 >> 2) * DM + (s0 & 3) * 8;
    const uint16_t* ga1 = Ab + (size_t)(s1 >> 2) * DM + (s1 & 3) * 8;
    const uint16_t* gb0 = Bb + (size_t)(s0 >> 2) * DM + (s0 & 3) * 8;

    gld16(ga0, &As[0][s0 * 8]);
    gld16(ga1, &As[0][s1 * 8]);
    gld16(gb0, &Bs[0][s0 * 8]);
    __syncthreads();

    for (int t = 0; t < 16; ++t) {
        const int kB = t * 64 + 32;
        gld16(ga0 + kB, &As[1][s0 * 8]);
        gld16(ga1 + kB, &As[1][s1 * 8]);
        gld16(gb0 + kB, &Bs[1][s0 * 8]);
        GO_STEP(As[0], Bs[0]);
        __syncthreads();

        if (t < 15) {
            const int kA = t * 64 + 64;
            gld16(ga0 + kA, &As[0][s0 * 8]);
            gld16(ga1 + kA, &As[0][s1 * 8]);
            gld16(gb0 + kA, &Bs[0][s0 * 8]);
        }
        GO_STEP(As[1], Bs[1]);
        __syncthreads();
    }

    const bool f32o = (*flagp != 0);
    #pragma unroll
    for (int tj = 0; tj < 2; ++tj) {
        const int c = bn + wn + tj * 16 + ln;
        const float bb = bf1(boc[c]);
        #pragma unroll
        for (int ti = 0; ti < 4; ++ti)
            #pragma unroll
            for (int r = 0; r < 4; ++r) {
                const int row = bm + wm + ti * 16 + quad * 4 + r;
                const float v = acc[ti][tj][r] + bb;
                if (f32o) ((float*)out)[(size_t)row * DM + c] = v;
                else      ((uint16_t*)out)[(size_t)row * DM + c] = f2bf(v);
            }
    }
}

// ============================================================
// Flash-style MFMA attention v13 VERBATIM (proven green R7/R9, 51us).
// FULL REVERT: R12's bisect proved s_setprio around the MFMA clusters
// corrupts results here (absmax 0.83 with ONLY setprio changed vs green
// R9/R10 components). Mechanism hypothesis: the setprio builtins create
// scheduling-region boundaries that let hipcc reorder the MFMA cluster
// relative to the inline-asm cvt_pk outputs / ds_read waits (rule-#18
// class). Lesson: trust the bisect over the "pure hint" semantic model.
// setprio arc CLOSED for this kernel.
// ============================================================
#define P_BUILD(SA, PA_LO, PA_HI)                                              \
  do {                                                                         \
    uint32_t c0_ = cvt_pk_bf16((SA)[0], (SA)[1]);                              \
    uint32_t c1_ = cvt_pk_bf16((SA)[2], (SA)[3]);                              \
    uint32_t c2_ = cvt_pk_bf16((SA)[4], (SA)[5]);                              \
    uint32_t c3_ = cvt_pk_bf16((SA)[6], (SA)[7]);                              \
    uint32_t c4_ = cvt_pk_bf16((SA)[8], (SA)[9]);                              \
    uint32_t c5_ = cvt_pk_bf16((SA)[10], (SA)[11]);                            \
    uint32_t c6_ = cvt_pk_bf16((SA)[12], (SA)[13]);                            \
    uint32_t c7_ = cvt_pk_bf16((SA)[14], (SA)[15]);                            \
    pl32(c0_, c2_); pl32(c1_, c3_);                                            \
    pl32(c4_, c6_); pl32(c5_, c7_);                                            \
    union { uint32_t u[4]; bf16x8 f; } lo_, hi_;                               \
    lo_.u[0] = c0_; lo_.u[1] = c1_; lo_.u[2] = c2_; lo_.u[3] = c3_;            \
    hi_.u[0] = c4_; hi_.u[1] = c5_; hi_.u[2] = c6_; hi_.u[3] = c7_;            \
    (PA_LO) = lo_.f; (PA_HI) = hi_.f;                                          \
  } while (0)

#define ATTN_COMPUTE(K0, KSB, VSB)                                             \
  do {                                                                         \
    const int mode_ = ((K0) >= q0 + 256) ? 0 : (((K0) + 192 <= q0) ? 2 : 1);   \
    bf16x8 kf_[2][4], vf_[2][4];                                               \
    _Pragma("unroll")                                                          \
    for (int kb = 0; kb < 2; ++kb)                                             \
      _Pragma("unroll")                                                        \
      for (int ds = 0; ds < 4; ++ds)                                           \
        kf_[kb][ds] = ld_frag((KSB) + kfo[kb][ds]);                            \
    _Pragma("unroll")                                                          \
    for (int db = 0; db < 2; ++db)                                             \
      _Pragma("unroll")                                                        \
      for (int kc = 0; kc < 4; ++kc)                                           \
        vf_[db][kc] = ld_frag((VSB) + vfo[db][kc]);                            \
    f32x16 sa0, sa1;                                                           \
    {                                                                          \
      const float binit_ = (mode_ == 0) ? bneg : ((mode_ == 2) ? bpos : 0.f);  \
      _Pragma("unroll")                                                        \
      for (int r = 0; r < 16; ++r) { sa0[r] = binit_; sa1[r] = binit_; }       \
    }                                                                          \
    _Pragma("unroll")                                                          \
    for (int ds = 0; ds < 4; ++ds) {                                           \
      sa0 = MFMA32(kf_[0][ds], qb[ds], sa0);                                   \
      sa1 = MFMA32(kf_[1][ds], qb[ds], sa1);                                   \
    }                                                                          \
    if (mode_ == 1) {                                                          \
      const int iq0_ = q0 + wave * 32 + l31 + 128 - (K0) - 4 * hi;             \
      _Pragma("unroll")                                                        \
      for (int r = 0; r < 16; ++r) {                                           \
        const int ko_ = (r & 3) + 8 * (r >> 2);                                \
        const int x0_ = max(0, min(256, iq0_ - ko_));                          \
        const int x1_ = max(0, min(256, iq0_ - 32 - ko_));                     \
        sa0[r] += bias_s[x0_];                                                 \
        sa1[r] += bias_s[x1_];                                                 \
      }                                                                        \
    }                                                                          \
    _Pragma("unroll")                                                          \
    for (int r = 0; r < 16; ++r) {                                             \
      sa0[r] = __builtin_amdgcn_exp2f(sa0[r]);                                 \
      sa1[r] = __builtin_amdgcn_exp2f(sa1[r]);                                 \
    }                                                                          \
    bf16x8 pa_[4];                                                             \
    P_BUILD(sa0, pa_[0], pa_[1]);                                              \
    P_BUILD(sa1, pa_[2], pa_[3]);                                              \
    _Pragma("unroll")                                                          \
    for (int kc = 0; kc < 4; ++kc) {                                           \
      lf    = MFMA32(pa_[kc], onef, lf);                                       \
      o2[0] = MFMA32(pa_[kc], vf_[0][kc], o2[0]);                              \
      o2[1] = MFMA32(pa_[kc], vf_[1][kc], o2[1]);                              \
    }                                                                          \
  } while (0)

__global__ __launch_bounds__(256, 2)
void attn_mfma(const uint16_t* __restrict__ Q, const uint16_t* __restrict__ K,
               const uint16_t* __restrict__ Vt, const void* __restrict__ rel,
               uint16_t* __restrict__ ctx, const int* __restrict__ flagp)
{
    __shared__ alignas(16) uint16_t Ks[2][64 * 64];   // [buf][key][d], swizzled, 16 KB
    __shared__ alignas(16) uint16_t Vls[2][64 * 64];  // [buf][d][key], swizzled, 16 KB
    __shared__ float bias_s[NBUCKET];                 // bias*log2e - C8

    const bool f32in = (*flagp != 0);
    const int tid = threadIdx.x, wave = tid >> 6, lane = tid & 63;
    const int l31 = lane & 31, hi = lane >> 5;

    const int blk = blockIdx.x;                         // 512 blocks
    const int bh = (blk & 7) * 4 + ((blk >> 3) & 3);    // XCD-aware bh spread
    const int qt = blk >> 5;                            // 16 q-tiles of 128 rows
    const int b = bh >> 4, h = bh & 15;
    const int q0 = qt * 128;

    const float C8 = 8.0f * LOG2E;   // fixed-max shift (in exp2 domain)
    for (int i = tid; i < NBUCKET; i += 256) {
        const float bv = f32in ? ((const float*)rel)[i * NH + h]
                               : bf1(((const uint16_t*)rel)[i * NH + h]);
        bias_s[i] = bv * LOG2E - C8;
    }

    // Q B-frags (32x32x16 B-layout): lane holds col q = l31, k = hi*8+j
    bf16x8 qb[4];
    {
        const uint16_t* qp = Q + ((size_t)bh * SEQ + q0 + wave * 32 + l31) * HD;
        #pragma unroll
        for (int ds = 0; ds < 4; ++ds)
            qb[ds] = ld_frag(qp + ds * 16 + hi * 8);
    }

    // ones B-frag for l = P · 1 (reads the same bf16 pa frags as PV)
    union { uint4 u; bf16x8 f; } onec;
    onec.u = (uint4){0x3F803F80u, 0x3F803F80u, 0x3F803F80u, 0x3F803F80u};
    const bf16x8 onef = onec.f;

    f32x16 o2[2], lf;
    #pragma unroll
    for (int r = 0; r < 16; ++r) { o2[0][r] = 0.f; o2[1][r] = 0.f; lf[r] = 0.f; }

    // ---- staging: 256 threads x 2 segments x 16 B = one 64x128B tile ----
    const int s0_ = tid, s1_ = tid + 256;
    const int r0_ = s0_ >> 3, c0s_ = (s0_ & 7) ^ (r0_ & 7);
    const int r1_ = s1_ >> 3, c1s_ = (s1_ & 7) ^ (r1_ & 7);
    const int koff0 = r0_ * HD + c0s_ * 8,  koff1 = r1_ * HD + c1s_ * 8;
    const int voff0 = r0_ * SEQ + c0s_ * 8, voff1 = r1_ * SEQ + c1s_ * 8;
    uint16_t* const kd00 = &Ks[0][s0_ * 8];
    uint16_t* const kd01 = &Ks[0][s1_ * 8];
    uint16_t* const kd10 = &Ks[1][s0_ * 8];
    uint16_t* const kd11 = &Ks[1][s1_ * 8];
    uint16_t* const vd00 = &Vls[0][s0_ * 8];
    uint16_t* const vd01 = &Vls[0][s1_ * 8];
    uint16_t* const vd10 = &Vls[1][s0_ * 8];
    uint16_t* const vd11 = &Vls[1][s1_ * 8];

    const uint16_t* kg = K  + (size_t)bh * SEQ * HD;   // +64*HD per tile
    const uint16_t* vg = Vt + (size_t)bh * HD * SEQ;   // +64 per tile

    // ---- k0-invariant LDS frag offsets (row&7 == l31&7 for both) ----
    const int swz = l31 & 7;
    int kfo[2][4], vfo[2][4];
    #pragma unroll
    for (int kb = 0; kb < 2; ++kb)
        #pragma unroll
        for (int ds = 0; ds < 4; ++ds)
            kfo[kb][ds] = (kb * 32 + l31) * 64 + ((ds * 2 + hi) ^ swz) * 8;
    #pragma unroll
    for (int db = 0; db < 2; ++db)
        #pragma unroll
        for (int kc = 0; kc < 4; ++kc)
            vfo[db][kc] = (db * 32 + l31) * 64 + ((kc * 2 + hi) ^ swz) * 8;

    // ---- prologue: stage tile 0 into buf0 ----
    gld16(kg + koff0, kd00); gld16(kg + koff1, kd01);
    gld16(vg + voff0, vd00); gld16(vg + voff1, vd01);
    kg += 64 * HD; vg += 64;
    __syncthreads();   // drains stage-0 + bias_s fill
    const float bneg = bias_s[0], bpos = bias_s[256];

    // ---- main loop: 16 double-iters, 1 barrier per k-tile ----
    for (int t = 0; t < 16; ++t) {
        // phase A: tile 2t in buf0; prefetch tile 2t+1 -> buf1
        gld16(kg + koff0, kd10); gld16(kg + koff1, kd11);
        gld16(vg + voff0, vd10); gld16(vg + voff1, vd11);
        kg += 64 * HD; vg += 64;
        ATTN_COMPUTE(t * 128, &Ks[0][0], &Vls[0][0]);
        __syncthreads();   // vmcnt(0) drain lands ~full phase after issue

        // phase B: tile 2t+1 in buf1; prefetch tile 2t+2 -> buf0
        if (t < 15) {
            gld16(kg + koff0, kd00); gld16(kg + koff1, kd01);
            gld16(vg + voff0, vd00); gld16(vg + voff1, vd01);
            kg += 64 * HD; vg += 64;
        }
        ATTN_COMPUTE(t * 128 + 64, &Ks[1][0], &Vls[1][0]);
        __syncthreads();
    }

    // ---- epilogue: lf[r] and o2[db][r] share the q=crow(r,hi) layout ----
    #pragma unroll
    for (int r = 0; r < 16; ++r) {
        const float inv = 1.0f / lf[r];
        const int qq = q0 + wave * 32 + (r & 3) + 8 * (r >> 2) + 4 * hi;
        #pragma unroll
        for (int db = 0; db < 2; ++db)
            ctx[(((size_t)b * SEQ + qq) * NH + h) * HD + db * 32 + l31] =
                f2bf(o2[db][r] * inv);
    }
}

// ============================================================
extern "C" void kernel_launch(void* const* d_in, const int* in_sizes, int n_in,
                              void* d_out, int out_size, void* d_ws, size_t ws_size,
                              hipStream_t stream)
{
    const void* x   = d_in[0];
    const void* Wq  = d_in[1];
    const void* bq  = d_in[2];
    const void* Wk  = d_in[3];
    const void* bk  = d_in[4];
    const void* Wv  = d_in[5];
    const void* bv  = d_in[6];
    const void* Wo  = d_in[7];
    const void* bo  = d_in[8];
    const void* rel = d_in[9];

    const size_t M4 = 4194304, M1 = 1048576;
    uint16_t* ws16 = (uint16_t*)d_ws;
    uint16_t* xc   = ws16;                    // 4M; reused as Cw after QKV GEMM
    uint16_t* Wqkv = ws16 + M4;               // 3M  [Wq;Wk;Wv]
    uint16_t* Woc  = ws16 + M4 + 3 * M1;      // 1M
    uint16_t* bqkv = ws16 + M4 + 4 * M1;      // 3072 [bq;bk;bv]
    uint16_t* boc  = bqkv + 3072;             // 1024
    uint16_t* Qw   = ws16 + M4 + 4 * M1 + 8192;
    uint16_t* Kw   = Qw + M4;
    uint16_t* Vt   = Kw + M4;
    int* flag = (int*)(Vt + M4);
    uint16_t* Cw = xc;   // overlay: xc dead after gemm_qkv

    convert_kernel<<<4098, 256, 0, stream>>>(x, Wq, Wk, Wv, Wo, bq, bk, bv, bo,
                                             ws16, flag);
    gemm_qkv<<<768, 256, 0, stream>>>(xc, Wqkv, bqkv, Qw, Kw, Vt);
    attn_mfma<<<512, 256, 0, stream>>>(Qw, Kw, Vt, rel, Cw, flag);
    gemm_out<<<512, 256, 0, stream>>>(Cw, Woc, boc, d_out, flag);
}

// Round 14
// 201.966 us; speedup vs baseline: 1.0294x; 1.0137x over previous
//
#include <hip/hip_runtime.h>
#include <hip/hip_bf16.h>
#include <cstdint>
#include <cstddef>

#define DEVI __device__ __forceinline__

static constexpr int SEQ = 2048;
static constexpr int DM  = 1024;
static constexpr int NH  = 16;
static constexpr int HD  = 64;
static constexpr int NTOK = 2 * SEQ;
static constexpr int NBUCKET = 257;
static constexpr float LOG2E = 1.44269504088896f;

typedef __attribute__((ext_vector_type(8))) short bf16x8;
typedef __attribute__((ext_vector_type(4))) float f32x4;
typedef __attribute__((ext_vector_type(16))) float f32x16;
typedef __attribute__((ext_vector_type(2))) unsigned int uint32x2;
#define MFMA16(a, b, c) __builtin_amdgcn_mfma_f32_16x16x32_bf16((a), (b), (c), 0, 0, 0)
#define MFMA32(a, b, c) __builtin_amdgcn_mfma_f32_32x32x16_bf16((a), (b), (c), 0, 0, 0)

DEVI float bf1(uint16_t u)  { return __uint_as_float(((uint32_t)u) << 16); }
DEVI uint16_t f2bf(float f) {
    uint32_t x = __float_as_uint(f);
    x += 0x7fffu + ((x >> 16) & 1u);   // RTNE
    return (uint16_t)(x >> 16);
}
DEVI bf16x8 ld_frag(const uint16_t* p) {
    union { uint4 u; bf16x8 f; } c;
    c.u = *(const uint4*)p;
    return c.f;
}
DEVI void gld16(const uint16_t* g, uint16_t* l) {
    __builtin_amdgcn_global_load_lds(
        (const __attribute__((address_space(1))) uint32_t*)g,
        (__attribute__((address_space(3))) uint32_t*)l, 16, 0, 0);
}
// Guide-verified T12 primitives (proven green in v13).
DEVI uint32_t cvt_pk_bf16(float lo, float hi) {
    uint32_t r;
    asm("v_cvt_pk_bf16_f32 %0, %1, %2" : "=v"(r) : "v"(lo), "v"(hi));
    return r;
}
DEVI void pl32(uint32_t &a, uint32_t &b) {
    const uint32x2 r = __builtin_amdgcn_permlane32_swap(a, b, false, false);
    a = r[0]; b = r[1];
}

// ============================================================
// convert v2: sniff merged in (green in R10/R13).
// ============================================================
__global__ __launch_bounds__(256)
void convert_kernel(const void* __restrict__ x, const void* __restrict__ Wq,
                    const void* __restrict__ Wk, const void* __restrict__ Wv,
                    const void* __restrict__ Wo, const void* __restrict__ bq,
                    const void* __restrict__ bk, const void* __restrict__ bv,
                    const void* __restrict__ bo, uint16_t* __restrict__ dst,
                    int* __restrict__ flag_out)
{
    __shared__ int f32s;
    if (threadIdx.x == 0) f32s = 0;
    __syncthreads();
    int bad = 0;
    for (int i = threadIdx.x; i < 512; i += 256) {
        const float v = bf1(((const uint16_t*)x)[i]);
        if (!(fabsf(v) < 64.0f)) bad = 1;
    }
    if (bad) f32s = 1;
    __syncthreads();
    const bool f32in = (f32s != 0);
    if (blockIdx.x == 0 && threadIdx.x == 0) *flag_out = f32in ? 1 : 0;

    const size_t M4 = 4194304, M1 = 1048576;
    const size_t e = ((size_t)blockIdx.x * 256 + threadIdx.x) * 8;
    const void* src; size_t off;
    if      (e < M4)                 { src = x;  off = e; }
    else if (e < M4 + M1)            { src = Wq; off = e - M4; }
    else if (e < M4 + 2*M1)          { src = Wk; off = e - M4 - M1; }
    else if (e < M4 + 3*M1)          { src = Wv; off = e - M4 - 2*M1; }
    else if (e < M4 + 4*M1)          { src = Wo; off = e - M4 - 3*M1; }
    else if (e < M4 + 4*M1 + 1024)   { src = bq; off = e - M4 - 4*M1; }
    else if (e < M4 + 4*M1 + 2048)   { src = bk; off = e - M4 - 4*M1 - 1024; }
    else if (e < M4 + 4*M1 + 3072)   { src = bv; off = e - M4 - 4*M1 - 2048; }
    else                             { src = bo; off = e - M4 - 4*M1 - 3072; }
    if (f32in) {
        const float4 a = *(const float4*)((const float*)src + off);
        const float4 b = *(const float4*)((const float*)src + off + 4);
        uint4 o;
        o.x = (uint32_t)f2bf(a.x) | ((uint32_t)f2bf(a.y) << 16);
        o.y = (uint32_t)f2bf(a.z) | ((uint32_t)f2bf(a.w) << 16);
        o.z = (uint32_t)f2bf(b.x) | ((uint32_t)f2bf(b.y) << 16);
        o.w = (uint32_t)f2bf(b.z) | ((uint32_t)f2bf(b.w) << 16);
        *(uint4*)(dst + e) = o;
    } else {
        *(uint4*)(dst + e) = *(const uint4*)((const uint16_t*)src + off);
    }
}

// ============================================================
// Shared 128x64-tile MFMA step (the gemm_out v2 geometry, green 3x):
// af[4] over 128 M-rows, bfr[2] over 64 N-rows, acc[4][2].
// ============================================================
#define GO_STEP(AS, BS)                                                        \
  do {                                                                         \
    bf16x8 af[4], bfr[2];                                                      \
    _Pragma("unroll")                                                          \
    for (int t4 = 0; t4 < 4; ++t4)                                             \
        af[t4] = ld_frag(&(AS)[(wm + t4 * 16 + ln) * 32 + quad * 8]);          \
    _Pragma("unroll")                                                          \
    for (int t2 = 0; t2 < 2; ++t2)                                             \
        bfr[t2] = ld_frag(&(BS)[(wn + t2 * 16 + ln) * 32 + quad * 8]);         \
    _Pragma("unroll")                                                          \
    for (int ti = 0; ti < 4; ++ti)                                             \
      _Pragma("unroll")                                                        \
      for (int tj = 0; tj < 2; ++tj)                                           \
        acc[ti][tj] = MFMA16(af[ti], bfr[tj], acc[ti][tj]);                    \
  } while (0)

// ============================================================
// Fused QKV MFMA GEMM v3: RE-TILED 128x128 -> 128x64 for occupancy.
// R13 counters: MfmaUtil 15%, VALU 20%, HBM 15%, Occ 16% — latency-bound
// and GRID-CAPPED at 768 blocks = exactly 3 blocks/CU (no packing lever
// can add blocks that don't exist). 128x64 tiles -> 1536 blocks = 6/CU
// (LDS 24 KB, launch_bounds(256,6) caps VGPR at 85 so all 6 pack).
// Structure is gemm_out v2's VERBATIM staging + GO_STEP (green 3x) —
// no fresh staging derivation. Epilogues keep the qkv formulas with
// tj<2; Q/K boundary (c=1024) is 64-aligned so no tile straddles it.
// Q output PRESCALED by 0.125*log2(e) for exp2 softmax.
// ============================================================
__global__ __launch_bounds__(256, 6)
void gemm_qkv(const uint16_t* __restrict__ xc, const uint16_t* __restrict__ Wqkv,
              const uint16_t* __restrict__ bqkv,
              uint16_t* __restrict__ Qw, uint16_t* __restrict__ Kw,
              uint16_t* __restrict__ Vt)
{
    __shared__ uint16_t As[2][128 * 32];
    __shared__ uint16_t Bs[2][64 * 32];
    const int tid = threadIdx.x, bx = blockIdx.x;
    const int lane = tid & 63, wave = tid >> 6;
    const int ln = lane & 15, quad = lane >> 4;
    const int wm = (wave & 1) * 64, wn = (wave >> 1) * 32;

    const uint16_t *Ab, *Bb;
    int bm, bn, vor;
    if (bx < 1024) {
        // xc[4096 x 1024] @ Wqkv[0:2048]^T -> Q|K ; tiles 32 x 32
        vor = 0; bm = (bx >> 5) * 128; bn = (bx & 31) * 64;
        Ab = xc + (size_t)bm * DM;  Bb = Wqkv + (size_t)bn * DM;
    } else {
        // Wv[1024 x 1024] @ xc^T -> Vt ; tiles 8 x 64
        vor = 1; const int b2 = bx - 1024; bm = (b2 >> 6) * 128; bn = (b2 & 63) * 64;
        Ab = Wqkv + (size_t)(2048 + bm) * DM;  Bb = xc + (size_t)bn * DM;
    }

    f32x4 acc[4][2];
    #pragma unroll
    for (int i = 0; i < 4; ++i)
        #pragma unroll
        for (int j = 0; j < 2; ++j) acc[i][j] = (f32x4){0.f, 0.f, 0.f, 0.f};

    const int s0 = tid, s1 = 256 + tid;
    const uint16_t* ga0 = Ab + (size_t)(s0 >> 2) * DM + (s0 & 3) * 8;
    const uint16_t* ga1 = Ab + (size_t)(s1 >> 2) * DM + (s1 & 3) * 8;
    const uint16_t* gb0 = Bb + (size_t)(s0 >> 2) * DM + (s0 & 3) * 8;

    gld16(ga0, &As[0][s0 * 8]);
    gld16(ga1, &As[0][s1 * 8]);
    gld16(gb0, &Bs[0][s0 * 8]);
    __syncthreads();

    for (int t = 0; t < 16; ++t) {
        const int kB = t * 64 + 32;
        gld16(ga0 + kB, &As[1][s0 * 8]);
        gld16(ga1 + kB, &As[1][s1 * 8]);
        gld16(gb0 + kB, &Bs[1][s0 * 8]);
        GO_STEP(As[0], Bs[0]);
        __syncthreads();

        if (t < 15) {
            const int kA = t * 64 + 64;
            gld16(ga0 + kA, &As[0][s0 * 8]);
            gld16(ga1 + kA, &As[0][s1 * 8]);
            gld16(gb0 + kA, &Bs[0][s0 * 8]);
        }
        GO_STEP(As[1], Bs[1]);
        __syncthreads();
    }

    if (!vor) {
        #pragma unroll
        for (int tj = 0; tj < 2; ++tj) {
            const int c = bn + wn + tj * 16 + ln;
            const int mat = c >> 10, h = (c >> 6) & 15, hd = c & 63;
            uint16_t* dstp = mat ? Kw : Qw;
            const float scale = mat ? 1.0f : (0.125f * LOG2E);
            const float bb = bf1(bqkv[c]);
            #pragma unroll
            for (int ti = 0; ti < 4; ++ti)
                #pragma unroll
                for (int r = 0; r < 4; ++r) {
                    const int row = bm + wm + ti * 16 + quad * 4 + r;
                    const int b = row >> 11, s = row & 2047;
                    dstp[(((size_t)b * NH + h) * SEQ + s) * HD + hd] =
                        f2bf((acc[ti][tj][r] + bb) * scale);
                }
        }
    } else {
        #pragma unroll
        for (int ti = 0; ti < 4; ++ti)
            #pragma unroll
            for (int r = 0; r < 4; ++r) {
                const int f = bm + wm + ti * 16 + quad * 4 + r;
                const int h = f >> 6, hd = f & 63;
                const float bb = bf1(bqkv[2048 + f]);
                #pragma unroll
                for (int tj = 0; tj < 2; ++tj) {
                    const int t = bn + wn + tj * 16 + ln;
                    const int b = t >> 11, s = t & 2047;
                    Vt[(((size_t)b * NH + h) * HD + hd) * SEQ + s] = f2bf(acc[ti][tj][r] + bb);
                }
            }
    }
}

// ============================================================
// Output projection v2 (green R9/R10/R13). out = Cw · Woc^T + bo.
// ============================================================
__global__ __launch_bounds__(256)
void gemm_out(const uint16_t* __restrict__ Cw, const uint16_t* __restrict__ Woc,
              const uint16_t* __restrict__ boc, void* __restrict__ out,
              const int* __restrict__ flagp)
{
    __shared__ uint16_t As[2][128 * 32];
    __shared__ uint16_t Bs[2][64 * 32];
    const int tid = threadIdx.x, bx = blockIdx.x;
    const int lane = tid & 63, wave = tid >> 6;
    const int ln = lane & 15, quad = lane >> 4;
    const int wm = (wave & 1) * 64, wn = (wave >> 1) * 32;
    const int bm = (bx >> 4) * 128, bn = (bx & 15) * 64;
    const uint16_t* Ab = Cw + (size_t)bm * DM;
    const uint16_t* Bb = Woc + (size_t)bn * DM;

    f32x4 acc[4][2];
    #pragma unroll
    for (int i = 0; i < 4; ++i)
        #pragma unroll
        for (int j = 0; j < 2; ++j) acc[i][j] = (f32x4){0.f, 0.f, 0.f, 0.f};

    const int s0 = tid, s1 = 256 + tid;
    const uint16_t* ga0 = Ab + (size_t)(s0 >> 2) * DM + (s0 & 3) * 8;
    const uint16_t* ga1 = Ab + (size_t)(s1 >> 2) * DM + (s1 & 3) * 8;
    const uint16_t* gb0 = Bb + (size_t)(s0 >> 2) * DM + (s0 & 3) * 8;

    gld16(ga0, &As[0][s0 * 8]);
    gld16(ga1, &As[0][s1 * 8]);
    gld16(gb0, &Bs[0][s0 * 8]);
    __syncthreads();

    for (int t = 0; t < 16; ++t) {
        const int kB = t * 64 + 32;
        gld16(ga0 + kB, &As[1][s0 * 8]);
        gld16(ga1 + kB, &As[1][s1 * 8]);
        gld16(gb0 + kB, &Bs[1][s0 * 8]);
        GO_STEP(As[0], Bs[0]);
        __syncthreads();

        if (t < 15) {
            const int kA = t * 64 + 64;
            gld16(ga0 + kA, &As[0][s0 * 8]);
            gld16(ga1 + kA, &As[0][s1 * 8]);
            gld16(gb0 + kA, &Bs[0][s0 * 8]);
        }
        GO_STEP(As[1], Bs[1]);
        __syncthreads();
    }

    const bool f32o = (*flagp != 0);
    #pragma unroll
    for (int tj = 0; tj < 2; ++tj) {
        const int c = bn + wn + tj * 16 + ln;
        const float bb = bf1(boc[c]);
        #pragma unroll
        for (int ti = 0; ti < 4; ++ti)
            #pragma unroll
            for (int r = 0; r < 4; ++r) {
                const int row = bm + wm + ti * 16 + quad * 4 + r;
                const float v = acc[ti][tj][r] + bb;
                if (f32o) ((float*)out)[(size_t)row * DM + c] = v;
                else      ((uint16_t*)out)[(size_t)row * DM + c] = f2bf(v);
            }
    }
}

// ============================================================
// Flash-style MFMA attention v13 VERBATIM (proven green R7/R9/R13,
// 51us). setprio arc CLOSED (R12 bisect: corrupts results here).
// ============================================================
#define P_BUILD(SA, PA_LO, PA_HI)                                              \
  do {                                                                         \
    uint32_t c0_ = cvt_pk_bf16((SA)[0], (SA)[1]);                              \
    uint32_t c1_ = cvt_pk_bf16((SA)[2], (SA)[3]);                              \
    uint32_t c2_ = cvt_pk_bf16((SA)[4], (SA)[5]);                              \
    uint32_t c3_ = cvt_pk_bf16((SA)[6], (SA)[7]);                              \
    uint32_t c4_ = cvt_pk_bf16((SA)[8], (SA)[9]);                              \
    uint32_t c5_ = cvt_pk_bf16((SA)[10], (SA)[11]);                            \
    uint32_t c6_ = cvt_pk_bf16((SA)[12], (SA)[13]);                            \
    uint32_t c7_ = cvt_pk_bf16((SA)[14], (SA)[15]);                            \
    pl32(c0_, c2_); pl32(c1_, c3_);                                            \
    pl32(c4_, c6_); pl32(c5_, c7_);                                            \
    union { uint32_t u[4]; bf16x8 f; } lo_, hi_;                               \
    lo_.u[0] = c0_; lo_.u[1] = c1_; lo_.u[2] = c2_; lo_.u[3] = c3_;            \
    hi_.u[0] = c4_; hi_.u[1] = c5_; hi_.u[2] = c6_; hi_.u[3] = c7_;            \
    (PA_LO) = lo_.f; (PA_HI) = hi_.f;                                          \
  } while (0)

#define ATTN_COMPUTE(K0, KSB, VSB)                                             \
  do {                                                                         \
    const int mode_ = ((K0) >= q0 + 256) ? 0 : (((K0) + 192 <= q0) ? 2 : 1);   \
    bf16x8 kf_[2][4], vf_[2][4];                                               \
    _Pragma("unroll")                                                          \
    for (int kb = 0; kb < 2; ++kb)                                             \
      _Pragma("unroll")                                                        \
      for (int ds = 0; ds < 4; ++ds)                                           \
        kf_[kb][ds] = ld_frag((KSB) + kfo[kb][ds]);                            \
    _Pragma("unroll")                                                          \
    for (int db = 0; db < 2; ++db)                                             \
      _Pragma("unroll")                                                        \
      for (int kc = 0; kc < 4; ++kc)                                           \
        vf_[db][kc] = ld_frag((VSB) + vfo[db][kc]);                            \
    f32x16 sa0, sa1;                                                           \
    {                                                                          \
      const float binit_ = (mode_ == 0) ? bneg : ((mode_ == 2) ? bpos : 0.f);  \
      _Pragma("unroll")                                                        \
      for (int r = 0; r < 16; ++r) { sa0[r] = binit_; sa1[r] = binit_; }       \
    }                                                                          \
    _Pragma("unroll")                                                          \
    for (int ds = 0; ds < 4; ++ds) {                                           \
      sa0 = MFMA32(kf_[0][ds], qb[ds], sa0);                                   \
      sa1 = MFMA32(kf_[1][ds], qb[ds], sa1);                                   \
    }                                                                          \
    if (mode_ == 1) {                                                          \
      const int iq0_ = q0 + wave * 32 + l31 + 128 - (K0) - 4 * hi;             \
      _Pragma("unroll")                                                        \
      for (int r = 0; r < 16; ++r) {                                           \
        const int ko_ = (r & 3) + 8 * (r >> 2);                                \
        const int x0_ = max(0, min(256, iq0_ - ko_));                          \
        const int x1_ = max(0, min(256, iq0_ - 32 - ko_));                     \
        sa0[r] += bias_s[x0_];                                                 \
        sa1[r] += bias_s[x1_];                                                 \
      }                                                                        \
    }                                                                          \
    _Pragma("unroll")                                                          \
    for (int r = 0; r < 16; ++r) {                                             \
      sa0[r] = __builtin_amdgcn_exp2f(sa0[r]);                                 \
      sa1[r] = __builtin_amdgcn_exp2f(sa1[r]);                                 \
    }                                                                          \
    bf16x8 pa_[4];                                                             \
    P_BUILD(sa0, pa_[0], pa_[1]);                                              \
    P_BUILD(sa1, pa_[2], pa_[3]);                                              \
    _Pragma("unroll")                                                          \
    for (int kc = 0; kc < 4; ++kc) {                                           \
      lf    = MFMA32(pa_[kc], onef, lf);                                       \
      o2[0] = MFMA32(pa_[kc], vf_[0][kc], o2[0]);                              \
      o2[1] = MFMA32(pa_[kc], vf_[1][kc], o2[1]);                              \
    }                                                                          \
  } while (0)

__global__ __launch_bounds__(256, 2)
void attn_mfma(const uint16_t* __restrict__ Q, const uint16_t* __restrict__ K,
               const uint16_t* __restrict__ Vt, const void* __restrict__ rel,
               uint16_t* __restrict__ ctx, const int* __restrict__ flagp)
{
    __shared__ alignas(16) uint16_t Ks[2][64 * 64];   // [buf][key][d], swizzled, 16 KB
    __shared__ alignas(16) uint16_t Vls[2][64 * 64];  // [buf][d][key], swizzled, 16 KB
    __shared__ float bias_s[NBUCKET];                 // bias*log2e - C8

    const bool f32in = (*flagp != 0);
    const int tid = threadIdx.x, wave = tid >> 6, lane = tid & 63;
    const int l31 = lane & 31, hi = lane >> 5;

    const int blk = blockIdx.x;                         // 512 blocks
    const int bh = (blk & 7) * 4 + ((blk >> 3) & 3);    // XCD-aware bh spread
    const int qt = blk >> 5;                            // 16 q-tiles of 128 rows
    const int b = bh >> 4, h = bh & 15;
    const int q0 = qt * 128;

    const float C8 = 8.0f * LOG2E;   // fixed-max shift (in exp2 domain)
    for (int i = tid; i < NBUCKET; i += 256) {
        const float bv = f32in ? ((const float*)rel)[i * NH + h]
                               : bf1(((const uint16_t*)rel)[i * NH + h]);
        bias_s[i] = bv * LOG2E - C8;
    }

    // Q B-frags (32x32x16 B-layout): lane holds col q = l31, k = hi*8+j
    bf16x8 qb[4];
    {
        const uint16_t* qp = Q + ((size_t)bh * SEQ + q0 + wave * 32 + l31) * HD;
        #pragma unroll
        for (int ds = 0; ds < 4; ++ds)
            qb[ds] = ld_frag(qp + ds * 16 + hi * 8);
    }

    // ones B-frag for l = P · 1 (reads the same bf16 pa frags as PV)
    union { uint4 u; bf16x8 f; } onec;
    onec.u = (uint4){0x3F803F80u, 0x3F803F80u, 0x3F803F80u, 0x3F803F80u};
    const bf16x8 onef = onec.f;

    f32x16 o2[2], lf;
    #pragma unroll
    for (int r = 0; r < 16; ++r) { o2[0][r] = 0.f; o2[1][r] = 0.f; lf[r] = 0.f; }

    // ---- staging: 256 threads x 2 segments x 16 B = one 64x128B tile ----
    const int s0_ = tid, s1_ = tid + 256;
    const int r0_ = s0_ >> 3, c0s_ = (s0_ & 7) ^ (r0_ & 7);
    const int r1_ = s1_ >> 3, c1s_ = (s1_ & 7) ^ (r1_ & 7);
    const int koff0 = r0_ * HD + c0s_ * 8,  koff1 = r1_ * HD + c1s_ * 8;
    const int voff0 = r0_ * SEQ + c0s_ * 8, voff1 = r1_ * SEQ + c1s_ * 8;
    uint16_t* const kd00 = &Ks[0][s0_ * 8];
    uint16_t* const kd01 = &Ks[0][s1_ * 8];
    uint16_t* const kd10 = &Ks[1][s0_ * 8];
    uint16_t* const kd11 = &Ks[1][s1_ * 8];
    uint16_t* const vd00 = &Vls[0][s0_ * 8];
    uint16_t* const vd01 = &Vls[0][s1_ * 8];
    uint16_t* const vd10 = &Vls[1][s0_ * 8];
    uint16_t* const vd11 = &Vls[1][s1_ * 8];

    const uint16_t* kg = K  + (size_t)bh * SEQ * HD;   // +64*HD per tile
    const uint16_t* vg = Vt + (size_t)bh * HD * SEQ;   // +64 per tile

    // ---- k0-invariant LDS frag offsets (row&7 == l31&7 for both) ----
    const int swz = l31 & 7;
    int kfo[2][4], vfo[2][4];
    #pragma unroll
    for (int kb = 0; kb < 2; ++kb)
        #pragma unroll
        for (int ds = 0; ds < 4; ++ds)
            kfo[kb][ds] = (kb * 32 + l31) * 64 + ((ds * 2 + hi) ^ swz) * 8;
    #pragma unroll
    for (int db = 0; db < 2; ++db)
        #pragma unroll
        for (int kc = 0; kc < 4; ++kc)
            vfo[db][kc] = (db * 32 + l31) * 64 + ((kc * 2 + hi) ^ swz) * 8;

    // ---- prologue: stage tile 0 into buf0 ----
    gld16(kg + koff0, kd00); gld16(kg + koff1, kd01);
    gld16(vg + voff0, vd00); gld16(vg + voff1, vd01);
    kg += 64 * HD; vg += 64;
    __syncthreads();   // drains stage-0 + bias_s fill
    const float bneg = bias_s[0], bpos = bias_s[256];

    // ---- main loop: 16 double-iters, 1 barrier per k-tile ----
    for (int t = 0; t < 16; ++t) {
        // phase A: tile 2t in buf0; prefetch tile 2t+1 -> buf1
        gld16(kg + koff0, kd10); gld16(kg + koff1, kd11);
        gld16(vg + voff0, vd10); gld16(vg + voff1, vd11);
        kg += 64 * HD; vg += 64;
        ATTN_COMPUTE(t * 128, &Ks[0][0], &Vls[0][0]);
        __syncthreads();   // vmcnt(0) drain lands ~full phase after issue

        // phase B: tile 2t+1 in buf1; prefetch tile 2t+2 -> buf0
        if (t < 15) {
            gld16(kg + koff0, kd00); gld16(kg + koff1, kd01);
            gld16(vg + voff0, vd00); gld16(vg + voff1, vd01);
            kg += 64 * HD; vg += 64;
        }
        ATTN_COMPUTE(t * 128 + 64, &Ks[1][0], &Vls[1][0]);
        __syncthreads();
    }

    // ---- epilogue: lf[r] and o2[db][r] share the q=crow(r,hi) layout ----
    #pragma unroll
    for (int r = 0; r < 16; ++r) {
        const float inv = 1.0f / lf[r];
        const int qq = q0 + wave * 32 + (r & 3) + 8 * (r >> 2) + 4 * hi;
        #pragma unroll
        for (int db = 0; db < 2; ++db)
            ctx[(((size_t)b * SEQ + qq) * NH + h) * HD + db * 32 + l31] =
                f2bf(o2[db][r] * inv);
    }
}

// ============================================================
extern "C" void kernel_launch(void* const* d_in, const int* in_sizes, int n_in,
                              void* d_out, int out_size, void* d_ws, size_t ws_size,
                              hipStream_t stream)
{
    const void* x   = d_in[0];
    const void* Wq  = d_in[1];
    const void* bq  = d_in[2];
    const void* Wk  = d_in[3];
    const void* bk  = d_in[4];
    const void* Wv  = d_in[5];
    const void* bv  = d_in[6];
    const void* Wo  = d_in[7];
    const void* bo  = d_in[8];
    const void* rel = d_in[9];

    const size_t M4 = 4194304, M1 = 1048576;
    uint16_t* ws16 = (uint16_t*)d_ws;
    uint16_t* xc   = ws16;                    // 4M; reused as Cw after QKV GEMM
    uint16_t* Wqkv = ws16 + M4;               // 3M  [Wq;Wk;Wv]
    uint16_t* Woc  = ws16 + M4 + 3 * M1;      // 1M
    uint16_t* bqkv = ws16 + M4 + 4 * M1;      // 3072 [bq;bk;bv]
    uint16_t* boc  = bqkv + 3072;             // 1024
    uint16_t* Qw   = ws16 + M4 + 4 * M1 + 8192;
    uint16_t* Kw   = Qw + M4;
    uint16_t* Vt   = Kw + M4;
    int* flag = (int*)(Vt + M4);
    uint16_t* Cw = xc;   // overlay: xc dead after gemm_qkv

    convert_kernel<<<4098, 256, 0, stream>>>(x, Wq, Wk, Wv, Wo, bq, bk, bv, bo,
                                             ws16, flag);
    gemm_qkv<<<1536, 256, 0, stream>>>(xc, Wqkv, bqkv, Qw, Kw, Vt);
    attn_mfma<<<512, 256, 0, stream>>>(Qw, Kw, Vt, rel, Cw, flag);
    gemm_out<<<512, 256, 0, stream>>>(Cw, Woc, boc, d_out, flag);
}